// Round 2
// baseline (1110.944 us; speedup 1.0000x reference)
//
#include <hip/hip_runtime.h>
#include <hip/hip_bf16.h>

typedef __hip_bfloat16 bf16;
typedef short bf16x8 __attribute__((ext_vector_type(8)));
typedef float f32x4 __attribute__((ext_vector_type(4)));

#define BB 2
#define LL 512
#define HH 2048
#define DI 4096
#define NST 16
#define KK 4
#define RR 128
#define BLM (BB*LL)   // 1024 rows

enum { MODE_PROJ = 0, MODE_XPROJ = 1, MODE_DT = 2, MODE_OUT = 3 };

__device__ __forceinline__ float sigmoidf_(float x) { return 1.f / (1.f + __expf(-x)); }

// pack two fp32 -> two bf16 (RNE) in one dword; x in low half (k-ascending)
__device__ __forceinline__ unsigned int bfpack(float a, float b) {
    __hip_bfloat162 h = __float22bfloat162_rn(make_float2(a, b));
    union { __hip_bfloat162 h; unsigned int u; } cv; cv.h = h;
    return cv.u;
}

// C = A(M,K;lda) @ B(N,K)^T, fp32 in (converted to bf16 at staging), fp32 accum,
// fp32 epilogue per mode. Requires M%128==0, K%32==0, lda%4==0. N guarded.
__global__ __launch_bounds__(256) void gemm_bt(
    const float* __restrict__ A, const float* __restrict__ Bw,
    int M, int N, int K, int lda,
    const float* __restrict__ bias,
    float* __restrict__ aux0, float* __restrict__ aux1,
    float* __restrict__ outb, int mode)
{
    __shared__ short sA[128 * 40];   // 128 rows x 32 k, padded to 40
    __shared__ short sB[128 * 40];
    const int tid = threadIdx.x;
    const int row0 = blockIdx.x * 128;
    const int col0 = blockIdx.y * 128;
    const int wave = tid >> 6;
    const int lane = tid & 63;
    const int wr = (wave >> 1) * 64;   // wave row offset within block tile
    const int wc = (wave & 1) * 64;    // wave col offset
    const int lr = lane & 15;
    const int kq = (lane >> 4) << 3;   // 0,8,16,24

    f32x4 acc[4][4] = {};

    const int r0 = tid >> 2;            // 0..63
    const int kc = (tid & 3) << 3;      // 0,8,16,24 (8 floats per thread per row)

    for (int k0 = 0; k0 < K; k0 += 32) {
        #pragma unroll
        for (int h2 = 0; h2 < 2; h2++) {
            int r = r0 + h2 * 64;
            const float* ap = A + (size_t)(row0 + r) * lda + k0 + kc;
            float4 a0 = *(const float4*)ap;
            float4 a1 = *(const float4*)(ap + 4);
            *(uint4*)(&sA[r * 40 + kc]) = make_uint4(
                bfpack(a0.x, a0.y), bfpack(a0.z, a0.w),
                bfpack(a1.x, a1.y), bfpack(a1.z, a1.w));
            int nb = col0 + r;
            uint4 vb = make_uint4(0u, 0u, 0u, 0u);
            if (nb < N) {
                const float* bp = Bw + (size_t)nb * K + k0 + kc;
                float4 b0 = *(const float4*)bp;
                float4 b1 = *(const float4*)(bp + 4);
                vb = make_uint4(bfpack(b0.x, b0.y), bfpack(b0.z, b0.w),
                                bfpack(b1.x, b1.y), bfpack(b1.z, b1.w));
            }
            *(uint4*)(&sB[r * 40 + kc]) = vb;
        }
        __syncthreads();
        bf16x8 af[4], bfg[4];
        #pragma unroll
        for (int i = 0; i < 4; i++) {
            af[i]  = *(const bf16x8*)(&sA[(wr + i * 16 + lr) * 40 + kq]);
            bfg[i] = *(const bf16x8*)(&sB[(wc + i * 16 + lr) * 40 + kq]);
        }
        #pragma unroll
        for (int i = 0; i < 4; i++)
            #pragma unroll
            for (int j = 0; j < 4; j++)
                acc[i][j] = __builtin_amdgcn_mfma_f32_16x16x32_bf16(af[i], bfg[j], acc[i][j], 0, 0, 0);
        __syncthreads();
    }

    const int drow = (lane >> 4) << 2;  // 0,4,8,12
    const int dcol = lane & 15;
    #pragma unroll
    for (int i = 0; i < 4; i++) {
        #pragma unroll
        for (int j = 0; j < 4; j++) {
            int n = col0 + wc + j * 16 + dcol;
            if (n >= N) continue;
            float bv = bias ? bias[n] : 0.f;
            #pragma unroll
            for (int r = 0; r < 4; r++) {
                int m = row0 + wr + i * 16 + drow + r;
                float v = acc[i][j][r];
                if (mode == MODE_PROJ) {
                    v += bv;
                    if (n < DI) aux0[(size_t)m * DI + n] = v;                       // h
                    else        aux1[(size_t)m * DI + (n - DI)] = v * sigmoidf_(v); // silu(gate)
                } else if (mode == MODE_XPROJ) {
                    aux0[(size_t)m * 160 + n] = v;                                  // sp (ts|B|C)
                } else if (mode == MODE_DT) {
                    v += bv;
                    v = fmaxf(v, 0.f) + log1pf(__expf(-fabsf(v)));                  // softplus
                    aux0[(size_t)m * DI + n] = v;
                } else { // MODE_OUT
                    outb[(size_t)m * N + n] = v + bv;
                }
            }
        }
    }
}

// depthwise causal conv K=4 + silu; fp32 in/out
__global__ __launch_bounds__(256) void conv_silu(
    const float* __restrict__ h, const float* __restrict__ conv_w,
    const float* __restrict__ conv_b, float* __restrict__ hs_f)
{
    int idx = blockIdx.x * 256 + threadIdx.x;   // (b*512+l)*4096 + d
    int d = idx & (DI - 1);
    int l = (idx >> 12) & (LL - 1);
    float acc = conv_b[d];
    #pragma unroll
    for (int k = 0; k < KK; k++) {
        int ls = l - (KK - 1) + k;
        if (ls >= 0) acc += h[(size_t)idx + (size_t)(ls - l) * DI] * conv_w[d * KK + k];
    }
    float s = acc * sigmoidf_(acc);
    hs_f[idx] = s;
}

// selective scan: thread = (b, d, n); 16-lane reduce over n per step.
// gy holds silu(gate) on входе; y is written over it (same addr, read-before-write
// in the same lane's program order -> race-free).
__global__ __launch_bounds__(256) void scan_kernel(
    const float* __restrict__ dt, const float* __restrict__ sp,
    const float* __restrict__ hs_f, float* gy,
    const float* __restrict__ A_log, const float* __restrict__ Dv)
{
    int tid = threadIdx.x;
    int n = tid & 15, g = tid >> 4;
    int b = blockIdx.x >> 8;                 // Di/16 = 256 blocks per batch
    int d = (blockIdx.x & 255) * 16 + g;
    float A = -__expf(A_log[d * NST + n]);
    float Dd = Dv[d];
    float s = 0.f;
    const float* spb = sp + (size_t)b * LL * 160;
    size_t base = (size_t)b * LL * DI + d;
    for (int l = 0; l < LL; l++) {
        size_t off = base + (size_t)l * DI;
        float dtv = dt[off];
        float hsv = hs_f[off];
        float Bn = spb[l * 160 + RR + n];
        float Cn = spb[l * 160 + RR + NST + n];
        s = __expf(dtv * A) * s + dtv * Bn * hsv;
        float p = s * Cn;
        p += __shfl_xor(p, 1);
        p += __shfl_xor(p, 2);
        p += __shfl_xor(p, 4);
        p += __shfl_xor(p, 8);
        if (n == 0) {
            float gv = gy[off];
            gy[off] = (p + hsv * Dd) * gv;
        }
    }
}

extern "C" void kernel_launch(void* const* d_in, const int* in_sizes, int n_in,
                              void* d_out, int out_size, void* d_ws, size_t ws_size,
                              hipStream_t stream)
{
    const float* x       = (const float*)d_in[0];
    const float* in_w    = (const float*)d_in[1];
    const float* in_b    = (const float*)d_in[2];
    const float* conv_w  = (const float*)d_in[3];
    const float* conv_b  = (const float*)d_in[4];
    const float* xproj_w = (const float*)d_in[5];
    const float* dt_w    = (const float*)d_in[6];
    const float* dt_b    = (const float*)d_in[7];
    const float* A_log   = (const float*)d_in[8];
    const float* Dv      = (const float*)d_in[9];
    const float* out_w   = (const float*)d_in[10];
    const float* out_b   = (const float*)d_in[11];
    float* out = (float*)d_out;

    char* ws = (char*)d_ws;
    float* h_dt = (float*)ws; ws += (size_t)BLM * DI * 4;   // h, then dt (aliased)
    float* gy   = (float*)ws; ws += (size_t)BLM * DI * 4;   // silu(gate), then y (aliased)
    float* hs_f = (float*)ws; ws += (size_t)BLM * DI * 4;   // hs
    float* sp_f = (float*)ws; ws += (size_t)BLM * 160 * 4;  // sp = ts|B|C
    // total ~51 MB

    // 1. proj = x @ in_w^T + in_b -> h (fp32), silu(gate) (fp32)
    gemm_bt<<<dim3(BLM / 128, (2 * DI) / 128), 256, 0, stream>>>(
        x, in_w, BLM, 2 * DI, HH, HH, in_b, h_dt, gy, nullptr, MODE_PROJ);
    // 2. depthwise conv + silu -> hs
    conv_silu<<<(BLM * DI) / 256, 256, 0, stream>>>(h_dt, conv_w, conv_b, hs_f);
    // 3. sp = hs @ xproj_w^T
    gemm_bt<<<dim3(BLM / 128, 2), 256, 0, stream>>>(
        hs_f, xproj_w, BLM, RR + 2 * NST, DI, DI, nullptr, sp_f, nullptr, nullptr, MODE_XPROJ);
    // 4. dt = softplus(ts @ dt_w^T + dt_b); ts = sp[:, :128] via lda=160
    gemm_bt<<<dim3(BLM / 128, DI / 128), 256, 0, stream>>>(
        sp_f, dt_w, BLM, DI, RR, 160, dt_b, h_dt, nullptr, nullptr, MODE_DT);
    // 5. selective scan -> y (over gate buffer)
    scan_kernel<<<BB * (DI / 16), 256, 0, stream>>>(h_dt, sp_f, hs_f, gy, A_log, Dv);
    // 6. out = y @ out_w^T + out_b
    gemm_bt<<<dim3(BLM / 128, HH / 128), 256, 0, stream>>>(
        gy, out_w, BLM, HH, DI, DI, out_b, nullptr, nullptr, out, MODE_OUT);
}

// Round 3
// 767.792 us; speedup vs baseline: 1.4469x; 1.4469x over previous
//
#include <hip/hip_runtime.h>
#include <hip/hip_bf16.h>

typedef __hip_bfloat16 bf16;
typedef short bf16x8 __attribute__((ext_vector_type(8)));
typedef float f32x4 __attribute__((ext_vector_type(4)));

#define BB 2
#define LL 512
#define HH 2048
#define DI 4096
#define NST 16
#define KK 4
#define RR 128
#define BLM (BB*LL)   // 1024 rows
#define CN 16         // scan chunks
#define LC (LL/CN)    // 32 steps per chunk

enum { MODE_PROJ = 0, MODE_XPROJ = 1, MODE_DT = 2, MODE_OUT = 3 };

__device__ __forceinline__ float sigmoidf_(float x) { return 1.f / (1.f + __expf(-x)); }

__device__ __forceinline__ unsigned int bfpack(float a, float b) {
    __hip_bfloat162 h = __float22bfloat162_rn(make_float2(a, b));
    union { __hip_bfloat162 h; unsigned int u; } cv; cv.h = h;
    return cv.u;
}

// C = A(M,K;lda) @ B(N,K)^T, fp32 in (bf16 at staging), fp32 accum.
// blockIdx.z = split-K slice (MODE_XPROJ uses atomicAdd epilogue).
__global__ __launch_bounds__(256) void gemm_bt(
    const float* __restrict__ A, const float* __restrict__ Bw,
    int M, int N, int K, int lda,
    const float* __restrict__ bias,
    float* __restrict__ aux0, float* __restrict__ aux1,
    float* __restrict__ outb, int mode)
{
    __shared__ short sA[128 * 40];
    __shared__ short sB[128 * 40];
    const int tid = threadIdx.x;
    const int row0 = blockIdx.x * 128;
    const int col0 = blockIdx.y * 128;
    const int wave = tid >> 6;
    const int lane = tid & 63;
    const int wr = (wave >> 1) * 64;
    const int wc = (wave & 1) * 64;
    const int lr = lane & 15;
    const int kq = (lane >> 4) << 3;

    const int kpb = K / gridDim.z;
    const int kbeg = blockIdx.z * kpb;
    const int kend = kbeg + kpb;

    f32x4 acc[4][4] = {};

    const int r0 = tid >> 2;
    const int kc = (tid & 3) << 3;

    for (int k0 = kbeg; k0 < kend; k0 += 32) {
        #pragma unroll
        for (int h2 = 0; h2 < 2; h2++) {
            int r = r0 + h2 * 64;
            const float* ap = A + (size_t)(row0 + r) * lda + k0 + kc;
            float4 a0 = *(const float4*)ap;
            float4 a1 = *(const float4*)(ap + 4);
            *(uint4*)(&sA[r * 40 + kc]) = make_uint4(
                bfpack(a0.x, a0.y), bfpack(a0.z, a0.w),
                bfpack(a1.x, a1.y), bfpack(a1.z, a1.w));
            int nb = col0 + r;
            uint4 vb = make_uint4(0u, 0u, 0u, 0u);
            if (nb < N) {
                const float* bp = Bw + (size_t)nb * K + k0 + kc;
                float4 b0 = *(const float4*)bp;
                float4 b1 = *(const float4*)(bp + 4);
                vb = make_uint4(bfpack(b0.x, b0.y), bfpack(b0.z, b0.w),
                                bfpack(b1.x, b1.y), bfpack(b1.z, b1.w));
            }
            *(uint4*)(&sB[r * 40 + kc]) = vb;
        }
        __syncthreads();
        bf16x8 af[4], bfg[4];
        #pragma unroll
        for (int i = 0; i < 4; i++) {
            af[i]  = *(const bf16x8*)(&sA[(wr + i * 16 + lr) * 40 + kq]);
            bfg[i] = *(const bf16x8*)(&sB[(wc + i * 16 + lr) * 40 + kq]);
        }
        #pragma unroll
        for (int i = 0; i < 4; i++)
            #pragma unroll
            for (int j = 0; j < 4; j++)
                acc[i][j] = __builtin_amdgcn_mfma_f32_16x16x32_bf16(af[i], bfg[j], acc[i][j], 0, 0, 0);
        __syncthreads();
    }

    const int drow = (lane >> 4) << 2;
    const int dcol = lane & 15;
    #pragma unroll
    for (int i = 0; i < 4; i++) {
        #pragma unroll
        for (int j = 0; j < 4; j++) {
            int n = col0 + wc + j * 16 + dcol;
            if (n >= N) continue;
            float bv = bias ? bias[n] : 0.f;
            #pragma unroll
            for (int r = 0; r < 4; r++) {
                int m = row0 + wr + i * 16 + drow + r;
                float v = acc[i][j][r];
                if (mode == MODE_PROJ) {
                    v += bv;
                    if (n < DI) aux0[(size_t)m * DI + n] = v;                       // h
                    else        aux1[(size_t)m * DI + (n - DI)] = v * sigmoidf_(v); // silu(gate)
                } else if (mode == MODE_XPROJ) {
                    atomicAdd(&aux0[(size_t)m * 160 + n], v);                       // sp (split-K)
                } else if (mode == MODE_DT) {
                    v += bv;
                    v = fmaxf(v, 0.f) + log1pf(__expf(-fabsf(v)));                  // softplus
                    aux0[(size_t)m * DI + n] = v;
                } else { // MODE_OUT
                    outb[(size_t)m * N + n] = v + bv;
                }
            }
        }
    }
}

// depthwise causal conv K=4 + silu; fp32 in/out
__global__ __launch_bounds__(256) void conv_silu(
    const float* __restrict__ h, const float* __restrict__ conv_w,
    const float* __restrict__ conv_b, float* __restrict__ hs_f)
{
    int idx = blockIdx.x * 256 + threadIdx.x;
    int d = idx & (DI - 1);
    int l = (idx >> 12) & (LL - 1);
    float acc = conv_b[d];
    #pragma unroll
    for (int k = 0; k < KK; k++) {
        int ls = l - (KK - 1) + k;
        if (ls >= 0) acc += h[(size_t)idx + (size_t)(ls - l) * DI] * conv_w[d * KK + k];
    }
    float s = acc * sigmoidf_(acc);
    hs_f[idx] = s;
}

// Chunked scan pass 1: per (b,d,chunk) thread computes P = prod(dA), S = local
// final state over its 32 steps, 16 n-states in registers. d = lane-fast -> all
// dt/hs loads coalesced 256B/wave; B broadcast.
__global__ __launch_bounds__(256) void scan_part1(
    const float* __restrict__ dt, const float* __restrict__ sp,
    const float* __restrict__ hs_f, const float* __restrict__ A_log,
    float* __restrict__ P_ws, float* __restrict__ S_ws)
{
    int bid = blockIdx.x;
    int c  = bid & (CN - 1);
    int db = (bid >> 4) & (DI / 256 - 1);
    int b  = bid >> 8;
    int d  = db * 256 + threadIdx.x;

    float A[NST], P[NST], S[NST];
    #pragma unroll
    for (int n = 0; n < NST; n++) {
        A[n] = -__expf(A_log[d * NST + n]);
        P[n] = 1.f; S[n] = 0.f;
    }
    const float* spb = sp + (size_t)b * LL * 160;
    size_t base = (size_t)b * LL * DI + d;
    for (int l = c * LC; l < (c + 1) * LC; l++) {
        size_t off = base + (size_t)l * DI;
        float dtv = dt[off];
        float hsv = hs_f[off];
        float dh = dtv * hsv;
        #pragma unroll
        for (int n = 0; n < NST; n++) {
            float a  = __expf(dtv * A[n]);
            float Bn = spb[l * 160 + RR + n];
            S[n] = a * S[n] + dh * Bn;
            P[n] *= a;
        }
    }
    size_t o = ((size_t)((b * CN + c) * DI) + d) * NST;
    #pragma unroll
    for (int q = 0; q < 4; q++) {
        *(float4*)&P_ws[o + q * 4] = make_float4(P[q*4], P[q*4+1], P[q*4+2], P[q*4+3]);
        *(float4*)&S_ws[o + q * 4] = make_float4(S[q*4], S[q*4+1], S[q*4+2], S[q*4+3]);
    }
}

// Pass 2: rebuild chunk-initial state from preceding (P,S), run local scan, emit y.
__global__ __launch_bounds__(256) void scan_part2(
    const float* __restrict__ dt, const float* __restrict__ sp,
    const float* __restrict__ hs_f, float* gy,
    const float* __restrict__ A_log, const float* __restrict__ Dv,
    const float* __restrict__ P_ws, const float* __restrict__ S_ws)
{
    int bid = blockIdx.x;
    int c  = bid & (CN - 1);
    int db = (bid >> 4) & (DI / 256 - 1);
    int b  = bid >> 8;
    int d  = db * 256 + threadIdx.x;

    float s[NST];
    #pragma unroll
    for (int n = 0; n < NST; n++) s[n] = 0.f;
    for (int j = 0; j < c; j++) {                // uniform per block
        size_t o = ((size_t)((b * CN + j) * DI) + d) * NST;
        #pragma unroll
        for (int q = 0; q < 4; q++) {
            float4 Pq = *(const float4*)&P_ws[o + q * 4];
            float4 Sq = *(const float4*)&S_ws[o + q * 4];
            s[q*4+0] = Pq.x * s[q*4+0] + Sq.x;
            s[q*4+1] = Pq.y * s[q*4+1] + Sq.y;
            s[q*4+2] = Pq.z * s[q*4+2] + Sq.z;
            s[q*4+3] = Pq.w * s[q*4+3] + Sq.w;
        }
    }

    float A[NST];
    #pragma unroll
    for (int n = 0; n < NST; n++) A[n] = -__expf(A_log[d * NST + n]);
    float Dd = Dv[d];

    const float* spb = sp + (size_t)b * LL * 160;
    size_t base = (size_t)b * LL * DI + d;
    for (int l = c * LC; l < (c + 1) * LC; l++) {
        size_t off = base + (size_t)l * DI;
        float dtv = dt[off];
        float hsv = hs_f[off];
        float dh = dtv * hsv;
        float y = 0.f;
        #pragma unroll
        for (int n = 0; n < NST; n++) {
            float a  = __expf(dtv * A[n]);
            float Bn = spb[l * 160 + RR + n];
            float Cn = spb[l * 160 + RR + NST + n];
            s[n] = a * s[n] + dh * Bn;
            y += s[n] * Cn;
        }
        float gv = gy[off];
        gy[off] = (y + hsv * Dd) * gv;
    }
}

extern "C" void kernel_launch(void* const* d_in, const int* in_sizes, int n_in,
                              void* d_out, int out_size, void* d_ws, size_t ws_size,
                              hipStream_t stream)
{
    const float* x       = (const float*)d_in[0];
    const float* in_w    = (const float*)d_in[1];
    const float* in_b    = (const float*)d_in[2];
    const float* conv_w  = (const float*)d_in[3];
    const float* conv_b  = (const float*)d_in[4];
    const float* xproj_w = (const float*)d_in[5];
    const float* dt_w    = (const float*)d_in[6];
    const float* dt_b    = (const float*)d_in[7];
    const float* A_log   = (const float*)d_in[8];
    const float* Dv      = (const float*)d_in[9];
    const float* out_w   = (const float*)d_in[10];
    const float* out_b   = (const float*)d_in[11];
    float* out = (float*)d_out;

    char* ws = (char*)d_ws;
    float* h_dt = (float*)ws; ws += (size_t)BLM * DI * 4;    // h, then dt (aliased)
    float* gy   = (float*)ws; ws += (size_t)BLM * DI * 4;    // silu(gate), then y (aliased)
    float* hs_f = (float*)ws; ws += (size_t)BLM * DI * 4;    // hs
    float* sp_f = (float*)ws; ws += (size_t)BLM * 160 * 4;   // sp = ts|B|C
    float* P_ws = (float*)ws; ws += (size_t)BB * CN * DI * NST * 4;  // 8 MB
    float* S_ws = (float*)ws; ws += (size_t)BB * CN * DI * NST * 4;  // 8 MB
    // total ~68 MB

    // 1. proj = x @ in_w^T + in_b -> h, silu(gate)
    gemm_bt<<<dim3(BLM / 128, (2 * DI) / 128, 1), 256, 0, stream>>>(
        x, in_w, BLM, 2 * DI, HH, HH, in_b, h_dt, gy, nullptr, MODE_PROJ);
    // 2. depthwise conv + silu -> hs
    conv_silu<<<(BLM * DI) / 256, 256, 0, stream>>>(h_dt, conv_w, conv_b, hs_f);
    // 3. sp = hs @ xproj_w^T (split-K=8, atomic accumulate)
    hipMemsetAsync(sp_f, 0, (size_t)BLM * 160 * 4, stream);
    gemm_bt<<<dim3(BLM / 128, 2, 8), 256, 0, stream>>>(
        hs_f, xproj_w, BLM, RR + 2 * NST, DI, DI, nullptr, sp_f, nullptr, nullptr, MODE_XPROJ);
    // 4. dt = softplus(ts @ dt_w^T + dt_b); ts = sp[:, :128] via lda=160
    gemm_bt<<<dim3(BLM / 128, DI / 128, 1), 256, 0, stream>>>(
        sp_f, dt_w, BLM, DI, RR, 160, dt_b, h_dt, nullptr, nullptr, MODE_DT);
    // 5. chunked selective scan -> y (over gate buffer)
    scan_part1<<<BB * (DI / 256) * CN, 256, 0, stream>>>(
        h_dt, sp_f, hs_f, A_log, P_ws, S_ws);
    scan_part2<<<BB * (DI / 256) * CN, 256, 0, stream>>>(
        h_dt, sp_f, hs_f, gy, A_log, Dv, P_ws, S_ws);
    // 6. out = y @ out_w^T + out_b
    gemm_bt<<<dim3(BLM / 128, HH / 128, 1), 256, 0, stream>>>(
        gy, out_w, BLM, HH, DI, DI, out_b, nullptr, nullptr, out, MODE_OUT);
}

// Round 4
// 430.798 us; speedup vs baseline: 2.5788x; 1.7823x over previous
//
#include <hip/hip_runtime.h>
#include <hip/hip_bf16.h>

typedef __hip_bfloat16 bf16;
typedef short bf16x8 __attribute__((ext_vector_type(8)));
typedef float f32x4 __attribute__((ext_vector_type(4)));

#define BB 2
#define LL 512
#define HH 2048
#define DI 4096
#define NST 16
#define KK 4
#define RR 128
#define BLM (BB*LL)   // 1024 rows
#define CN 16         // scan chunks
#define LC (LL/CN)    // 32 steps per chunk

enum { MODE_PROJ = 0, MODE_XPROJ = 1, MODE_DT = 2, MODE_OUT = 3 };

__device__ __forceinline__ float sigmoidf_(float x) { return 1.f / (1.f + __expf(-x)); }
__device__ __forceinline__ float softplusf_(float x) {
    return fmaxf(x, 0.f) + log1pf(__expf(-fabsf(x)));
}
__device__ __forceinline__ unsigned int bfpack(float a, float b) {
    __hip_bfloat162 h = __float22bfloat162_rn(make_float2(a, b));
    union { __hip_bfloat162 h; unsigned int u; } cv; cv.h = h;
    return cv.u;
}

typedef const __attribute__((address_space(1))) unsigned int* gas_t;
typedef __attribute__((address_space(3))) unsigned int* las_t;
__device__ __forceinline__ void gld16(const void* g, void* l) {
    __builtin_amdgcn_global_load_lds((gas_t)g, (las_t)l, 16, 0, 0);
}

// fp32 -> bf16 elementwise (vectorized x4), grid-stride
__global__ __launch_bounds__(256) void cvt_f32_bf16(
    const float* __restrict__ src, bf16* __restrict__ dst, int n4)
{
    int i = blockIdx.x * 256 + threadIdx.x;
    int stride = gridDim.x * 256;
    for (; i < n4; i += stride) {
        float4 v = ((const float4*)src)[i];
        uint2 o; o.x = bfpack(v.x, v.y); o.y = bfpack(v.z, v.w);
        ((uint2*)dst)[i] = o;
    }
}

// extract sp[:, 0:128] (stride 160) -> ts bf16 (stride 128); exact grid 128x256
__global__ __launch_bounds__(256) void cvt_ts(
    const float* __restrict__ sp, bf16* __restrict__ ts)
{
    int i = blockIdx.x * 256 + threadIdx.x;   // 32768 float4 groups
    int row = i >> 5, c4 = (i & 31) << 2;
    float4 v = *(const float4*)&sp[(size_t)row * 160 + c4];
    uint2 o; o.x = bfpack(v.x, v.y); o.y = bfpack(v.z, v.w);
    *(uint2*)&ts[(size_t)row * RR + c4] = o;
}

// C = A(M,K;lda)bf16 @ B(N,K;ldb)^T bf16, fp32 accum, m97-style global_load_lds
// staging (unpadded LDS, wave-uniform base + lane*16). gridDim.z = split-K.
template<int BM, int MODE>
__global__ __launch_bounds__(256) void gemm_bf16(
    const bf16* __restrict__ A, const bf16* __restrict__ Bw,
    int N, int K, int lda, int ldb,
    const float* __restrict__ bias,
    float* __restrict__ outf, bf16* __restrict__ outh)
{
    __shared__ short sA[BM * 32];
    __shared__ short sB[128 * 32];
    const int tid = threadIdx.x;
    const int row0 = blockIdx.x * BM;
    const int col0 = blockIdx.y * 128;
    const int wave = tid >> 6;
    const int lane = tid & 63;
    constexpr int NJ = (BM == 128) ? 4 : 2;
    const int wr = (BM == 128) ? ((wave >> 1) * 64) : 0;
    const int wc = (BM == 128) ? ((wave & 1) * 64) : (wave * 32);
    const int lr = lane & 15;
    const int kq = (lane >> 4) << 3;

    const int kpb = K / gridDim.z;
    const int kbeg = blockIdx.z * kpb;
    const int kend = kbeg + kpb;

    const int r0 = tid >> 2;            // 0..63
    const int kc = (tid & 3) << 3;      // 0,8,16,24

    f32x4 acc[4][NJ] = {};

    for (int k0 = kbeg; k0 < kend; k0 += 32) {
        #pragma unroll
        for (int p = 0; p < BM / 64; p++) {
            int r = r0 + p * 64;
            gld16(A + (size_t)(row0 + r) * lda + k0 + kc, &sA[r * 32 + kc]);
        }
        #pragma unroll
        for (int p = 0; p < 2; p++) {
            int rr = r0 + p * 64;
            int nb = col0 + rr; if (nb > N - 1) nb = N - 1;   // clamp (epilogue guards)
            gld16(Bw + (size_t)nb * ldb + k0 + kc, &sB[rr * 32 + kc]);
        }
        __syncthreads();
        bf16x8 af[4], bfr[NJ];
        #pragma unroll
        for (int i = 0; i < 4; i++)
            af[i] = *(const bf16x8*)(&sA[(wr + i * 16 + lr) * 32 + kq]);
        #pragma unroll
        for (int j = 0; j < NJ; j++)
            bfr[j] = *(const bf16x8*)(&sB[(wc + j * 16 + lr) * 32 + kq]);
        #pragma unroll
        for (int i = 0; i < 4; i++)
            #pragma unroll
            for (int j = 0; j < NJ; j++)
                acc[i][j] = __builtin_amdgcn_mfma_f32_16x16x32_bf16(af[i], bfr[j], acc[i][j], 0, 0, 0);
        __syncthreads();
    }

    const int drow = (lane >> 4) << 2;
    const int dcol = lane & 15;
    #pragma unroll
    for (int i = 0; i < 4; i++) {
        #pragma unroll
        for (int j = 0; j < NJ; j++) {
            int n = col0 + wc + j * 16 + dcol;
            if (n >= N) continue;
            float bv = bias ? bias[n] : 0.f;
            #pragma unroll
            for (int r = 0; r < 4; r++) {
                int m = row0 + wr + i * 16 + drow + r;
                float v = acc[i][j][r];
                if (MODE == MODE_PROJ) {
                    v += bv;
                    if (n < DI) outf[(size_t)m * DI + n] = v;               // h raw
                    else        outh[(size_t)m * DI + (n - DI)] = (bf16)v;  // gate raw bf16
                } else if (MODE == MODE_XPROJ) {
                    atomicAdd(&outf[(size_t)m * 160 + n], v);               // sp (split-K)
                } else if (MODE == MODE_DT) {
                    outf[(size_t)m * DI + n] = v + bv;                      // dt raw
                } else { // MODE_OUT (split-K)
                    float add = (blockIdx.z == 0) ? bv : 0.f;
                    atomicAdd(&outf[(size_t)m * HH + n], v + add);
                }
            }
        }
    }
}

// depthwise causal conv K=4 + silu; fp32 in, bf16 out
__global__ __launch_bounds__(256) void conv_silu(
    const float* __restrict__ h, const float* __restrict__ conv_w,
    const float* __restrict__ conv_b, bf16* __restrict__ hs_b)
{
    int idx = blockIdx.x * 256 + threadIdx.x;
    int d = idx & (DI - 1);
    int l = (idx >> 12) & (LL - 1);
    float acc = conv_b[d];
    #pragma unroll
    for (int k = 0; k < KK; k++) {
        int ls = l - (KK - 1) + k;
        if (ls >= 0) acc += h[(size_t)idx + (size_t)(ls - l) * DI] * conv_w[d * KK + k];
    }
    float s = acc * sigmoidf_(acc);
    hs_b[idx] = (bf16)s;
}

// Chunked scan pass 1: per (b,d,chunk) thread; softplus(dt) inline, hs from bf16.
__global__ __launch_bounds__(256) void scan_part1(
    const float* __restrict__ dtr, const float* __restrict__ sp,
    const bf16* __restrict__ hs_b, const float* __restrict__ A_log,
    float* __restrict__ P_ws, float* __restrict__ S_ws)
{
    int bid = blockIdx.x;
    int c  = bid & (CN - 1);
    int db = (bid >> 4) & (DI / 256 - 1);
    int b  = bid >> 8;
    int d  = db * 256 + threadIdx.x;

    float A[NST], P[NST], S[NST];
    #pragma unroll
    for (int n = 0; n < NST; n++) {
        A[n] = -__expf(A_log[d * NST + n]);
        P[n] = 1.f; S[n] = 0.f;
    }
    const float* spb = sp + (size_t)b * LL * 160;
    size_t base = (size_t)b * LL * DI + d;
    for (int l = c * LC; l < (c + 1) * LC; l++) {
        size_t off = base + (size_t)l * DI;
        float dtv = softplusf_(dtr[off]);
        float hsv = (float)hs_b[off];
        float dh = dtv * hsv;
        #pragma unroll
        for (int n = 0; n < NST; n++) {
            float a  = __expf(dtv * A[n]);
            float Bn = spb[l * 160 + RR + n];
            S[n] = a * S[n] + dh * Bn;
            P[n] *= a;
        }
    }
    size_t o = ((size_t)((b * CN + c) * DI) + d) * NST;
    #pragma unroll
    for (int q = 0; q < 4; q++) {
        *(float4*)&P_ws[o + q * 4] = make_float4(P[q*4], P[q*4+1], P[q*4+2], P[q*4+3]);
        *(float4*)&S_ws[o + q * 4] = make_float4(S[q*4], S[q*4+1], S[q*4+2], S[q*4+3]);
    }
}

// Pass 2: rebuild chunk-initial state, local scan, silu(gate) inline, emit y bf16.
__global__ __launch_bounds__(256) void scan_part2(
    const float* __restrict__ dtr, const float* __restrict__ sp,
    const bf16* __restrict__ hs_b, const bf16* __restrict__ g_b,
    const float* __restrict__ A_log, const float* __restrict__ Dv,
    const float* __restrict__ P_ws, const float* __restrict__ S_ws,
    bf16* __restrict__ y_b)
{
    int bid = blockIdx.x;
    int c  = bid & (CN - 1);
    int db = (bid >> 4) & (DI / 256 - 1);
    int b  = bid >> 8;
    int d  = db * 256 + threadIdx.x;

    float s[NST];
    #pragma unroll
    for (int n = 0; n < NST; n++) s[n] = 0.f;
    for (int j = 0; j < c; j++) {
        size_t o = ((size_t)((b * CN + j) * DI) + d) * NST;
        #pragma unroll
        for (int q = 0; q < 4; q++) {
            float4 Pq = *(const float4*)&P_ws[o + q * 4];
            float4 Sq = *(const float4*)&S_ws[o + q * 4];
            s[q*4+0] = Pq.x * s[q*4+0] + Sq.x;
            s[q*4+1] = Pq.y * s[q*4+1] + Sq.y;
            s[q*4+2] = Pq.z * s[q*4+2] + Sq.z;
            s[q*4+3] = Pq.w * s[q*4+3] + Sq.w;
        }
    }

    float A[NST];
    #pragma unroll
    for (int n = 0; n < NST; n++) A[n] = -__expf(A_log[d * NST + n]);
    float Dd = Dv[d];

    const float* spb = sp + (size_t)b * LL * 160;
    size_t base = (size_t)b * LL * DI + d;
    for (int l = c * LC; l < (c + 1) * LC; l++) {
        size_t off = base + (size_t)l * DI;
        float dtv = softplusf_(dtr[off]);
        float hsv = (float)hs_b[off];
        float dh = dtv * hsv;
        float y = 0.f;
        #pragma unroll
        for (int n = 0; n < NST; n++) {
            float a  = __expf(dtv * A[n]);
            float Bn = spb[l * 160 + RR + n];
            float Cn = spb[l * 160 + RR + NST + n];
            s[n] = a * s[n] + dh * Bn;
            y += s[n] * Cn;
        }
        float gv = (float)g_b[off];
        y_b[off] = (bf16)((y + hsv * Dd) * (gv * sigmoidf_(gv)));
    }
}

extern "C" void kernel_launch(void* const* d_in, const int* in_sizes, int n_in,
                              void* d_out, int out_size, void* d_ws, size_t ws_size,
                              hipStream_t stream)
{
    const float* x       = (const float*)d_in[0];
    const float* in_w    = (const float*)d_in[1];
    const float* in_b    = (const float*)d_in[2];
    const float* conv_w  = (const float*)d_in[3];
    const float* conv_b  = (const float*)d_in[4];
    const float* xproj_w = (const float*)d_in[5];
    const float* dt_w    = (const float*)d_in[6];
    const float* dt_b    = (const float*)d_in[7];
    const float* A_log   = (const float*)d_in[8];
    const float* Dv      = (const float*)d_in[9];
    const float* out_w   = (const float*)d_in[10];
    const float* out_b   = (const float*)d_in[11];
    float* out = (float*)d_out;

    // Workspace with overlays (63.1 MB total):
    //  [0,32 MB):  in_w_b during dispatches 0-1; then P(8)|S(8)|y_b(8)|hs_b(8);
    //              out_w_b re-occupies [0,16) after scan_part2 (P,S dead).
    char* ws = (char*)d_ws;
    const size_t MB = 1u << 20;
    float* P_ws   = (float*)(ws + 0 * MB);
    float* S_ws   = (float*)(ws + 8 * MB);
    bf16*  y_b    = (bf16*)(ws + 16 * MB);
    bf16*  hs_b   = (bf16*)(ws + 24 * MB);
    bf16*  in_w_b = (bf16*)(ws + 0 * MB);   // overlay
    bf16*  out_w_b= (bf16*)(ws + 0 * MB);   // overlay (after scan)
    char* p = ws + 32 * MB;
    float* h_dt = (float*)p; p += (size_t)BLM * DI * 4;        // h raw, then dt raw
    bf16*  g_b  = (bf16*)p;  p += (size_t)BLM * DI * 2;        // gate raw bf16
    float* sp_f = (float*)p; p += (size_t)BLM * 160 * 4;       // sp = ts|B|C
    bf16*  ts_b = (bf16*)p;  p += (size_t)BLM * RR * 2;
    bf16*  xw_b = (bf16*)p;  p += (size_t)(RR + 2 * NST) * DI * 2;
    bf16*  dtw_b= (bf16*)p;  p += (size_t)DI * RR * 2;
    bf16*  x_b  = (bf16*)p;  p += (size_t)BLM * HH * 2;

    // 0. convert x + weights (except out_w) to bf16
    cvt_f32_bf16<<<512, 256, 0, stream>>>(x, x_b, BLM * HH / 4);
    cvt_f32_bf16<<<512, 256, 0, stream>>>(in_w, in_w_b, 2 * DI * HH / 4);
    cvt_f32_bf16<<<512, 256, 0, stream>>>(xproj_w, xw_b, (RR + 2 * NST) * DI / 4);
    cvt_f32_bf16<<<512, 256, 0, stream>>>(dt_w, dtw_b, DI * RR / 4);
    // 1. proj = x @ in_w^T + in_b -> h raw fp32, gate raw bf16
    gemm_bf16<128, MODE_PROJ><<<dim3(BLM / 128, (2 * DI) / 128, 1), 256, 0, stream>>>(
        x_b, in_w_b, 2 * DI, HH, HH, HH, in_b, h_dt, g_b);
    // 2. conv + silu -> hs bf16
    conv_silu<<<(BLM * DI) / 256, 256, 0, stream>>>(h_dt, conv_w, conv_b, hs_b);
    // 3. sp = hs @ xproj_w^T (BM=64, split-K=16, atomic)
    hipMemsetAsync(sp_f, 0, (size_t)BLM * 160 * 4, stream);
    gemm_bf16<64, MODE_XPROJ><<<dim3(BLM / 64, 2, 16), 256, 0, stream>>>(
        hs_b, xw_b, RR + 2 * NST, DI, DI, DI, nullptr, sp_f, nullptr);
    // 4. ts = bf16(sp[:, :128])
    cvt_ts<<<128, 256, 0, stream>>>(sp_f, ts_b);
    // 5. dt raw = ts @ dt_w^T + dt_b (BM=64; softplus applied in scan)
    gemm_bf16<64, MODE_DT><<<dim3(BLM / 64, DI / 128, 1), 256, 0, stream>>>(
        ts_b, dtw_b, DI, RR, RR, RR, dt_b, h_dt, nullptr);
    // 6-7. chunked scan -> y bf16
    scan_part1<<<BB * (DI / 256) * CN, 256, 0, stream>>>(
        h_dt, sp_f, hs_b, A_log, P_ws, S_ws);
    scan_part2<<<BB * (DI / 256) * CN, 256, 0, stream>>>(
        h_dt, sp_f, hs_b, g_b, A_log, Dv, P_ws, S_ws, y_b);
    // 8. convert out_w (into dead P/S region)
    cvt_f32_bf16<<<512, 256, 0, stream>>>(out_w, out_w_b, HH * DI / 4);
    // 9. out = y @ out_w^T + out_b (BM=128, split-K=4, atomic into zeroed d_out)
    hipMemsetAsync(out, 0, (size_t)BLM * HH * 4, stream);
    gemm_bf16<128, MODE_OUT><<<dim3(BLM / 128, HH / 128, 4), 256, 0, stream>>>(
        y_b, out_w_b, HH, DI, DI, DI, out_b, out, nullptr);
}

// Round 5
// 407.079 us; speedup vs baseline: 2.7291x; 1.0583x over previous
//
#include <hip/hip_runtime.h>
#include <hip/hip_bf16.h>

typedef __hip_bfloat16 bf16;
typedef short bf16x8 __attribute__((ext_vector_type(8)));
typedef float f32x4 __attribute__((ext_vector_type(4)));

#define BB 2
#define LL 512
#define HH 2048
#define DI 4096
#define NST 16
#define KK 4
#define RR 128
#define BLM (BB*LL)   // 1024 rows
#define CN 16         // scan chunks
#define LC (LL/CN)    // 32 steps per chunk
#define ZXP 16        // xproj split-K
#define ZOUT 4        // out split-K

enum { MODE_PROJ = 0, MODE_XPROJ = 1, MODE_DT = 2, MODE_OUT = 3 };

__device__ __forceinline__ float sigmoidf_(float x) { return 1.f / (1.f + __expf(-x)); }
__device__ __forceinline__ float softplusf_(float x) {
    return fmaxf(x, 0.f) + log1pf(__expf(-fabsf(x)));
}
__device__ __forceinline__ unsigned int bfpack(float a, float b) {
    __hip_bfloat162 h = __float22bfloat162_rn(make_float2(a, b));
    union { __hip_bfloat162 h; unsigned int u; } cv; cv.h = h;
    return cv.u;
}

typedef const __attribute__((address_space(1))) unsigned int* gas_t;
typedef __attribute__((address_space(3))) unsigned int* las_t;
__device__ __forceinline__ void gld16(const void* g, void* l) {
    __builtin_amdgcn_global_load_lds((gas_t)g, (las_t)l, 16, 0, 0);
}

// fp32 -> bf16 elementwise (vectorized x4), grid-stride
__global__ __launch_bounds__(256) void cvt_f32_bf16(
    const float* __restrict__ src, bf16* __restrict__ dst, int n4)
{
    int i = blockIdx.x * 256 + threadIdx.x;
    int stride = gridDim.x * 256;
    for (; i < n4; i += stride) {
        float4 v = ((const float4*)src)[i];
        uint2 o; o.x = bfpack(v.x, v.y); o.y = bfpack(v.z, v.w);
        ((uint2*)dst)[i] = o;
    }
}

// C = A(M,K;lda) @ B(N,K;ldb)^T, fp32 accum. blockIdx.x = COL tile (XCD swizzle:
// same-col blocks share linear%8 when gridDim.x%8==0), blockIdx.y = row tile,
// blockIdx.z = split-K slice. AF32: stage A from fp32 via VGPR+pack; else
// global_load_lds. No atomics: split-K modes store plain per-slice partials.
template<int BM, int MODE, bool AF32>
__global__ __launch_bounds__(256) void gemm_bf16(
    const void* __restrict__ Ap, const bf16* __restrict__ Bw,
    int N, int K, int lda, int ldb,
    const float* __restrict__ bias,
    float* __restrict__ outf, bf16* __restrict__ outh,
    float* __restrict__ s0, float* __restrict__ s1,
    float* __restrict__ s2, float* __restrict__ s3)
{
    __shared__ short sA[BM * 32];
    __shared__ short sB[128 * 32];
    const int tid = threadIdx.x;
    const int col0 = blockIdx.x * 128;
    const int row0 = blockIdx.y * BM;
    const int wave = tid >> 6;
    const int lane = tid & 63;
    constexpr int NJ = (BM == 128) ? 4 : 2;
    const int wr = (BM == 128) ? ((wave >> 1) * 64) : 0;
    const int wc = (BM == 128) ? ((wave & 1) * 64) : (wave * 32);
    const int lr = lane & 15;
    const int kq = (lane >> 4) << 3;

    const int kpb = K / gridDim.z;
    const int kbeg = blockIdx.z * kpb;
    const int kend = kbeg + kpb;

    const int r0 = tid >> 2;            // 0..63
    const int kc = (tid & 3) << 3;      // 0,8,16,24

    f32x4 acc[4][NJ] = {};

    for (int k0 = kbeg; k0 < kend; k0 += 32) {
        #pragma unroll
        for (int p = 0; p < BM / 64; p++) {
            int r = r0 + p * 64;
            if (AF32) {
                const float* ap = (const float*)Ap + (size_t)(row0 + r) * lda + k0 + kc;
                float4 a0 = *(const float4*)ap;
                float4 a1 = *(const float4*)(ap + 4);
                *(uint4*)(&sA[r * 32 + kc]) = make_uint4(
                    bfpack(a0.x, a0.y), bfpack(a0.z, a0.w),
                    bfpack(a1.x, a1.y), bfpack(a1.z, a1.w));
            } else {
                gld16((const bf16*)Ap + (size_t)(row0 + r) * lda + k0 + kc,
                      &sA[r * 32 + kc]);
            }
        }
        #pragma unroll
        for (int p = 0; p < 2; p++) {
            int rr = r0 + p * 64;
            int nb = col0 + rr; if (nb > N - 1) nb = N - 1;   // clamp (epilogue guards)
            gld16(Bw + (size_t)nb * ldb + k0 + kc, &sB[rr * 32 + kc]);
        }
        __syncthreads();
        bf16x8 af[4], bfr[NJ];
        #pragma unroll
        for (int i = 0; i < 4; i++)
            af[i] = *(const bf16x8*)(&sA[(wr + i * 16 + lr) * 32 + kq]);
        #pragma unroll
        for (int j = 0; j < NJ; j++)
            bfr[j] = *(const bf16x8*)(&sB[(wc + j * 16 + lr) * 32 + kq]);
        #pragma unroll
        for (int i = 0; i < 4; i++)
            #pragma unroll
            for (int j = 0; j < NJ; j++)
                acc[i][j] = __builtin_amdgcn_mfma_f32_16x16x32_bf16(af[i], bfr[j], acc[i][j], 0, 0, 0);
        __syncthreads();
    }

    float* oslice = outf;
    if (MODE == MODE_OUT) {
        int z = blockIdx.z;
        oslice = (z == 0) ? s0 : (z == 1) ? s1 : (z == 2) ? s2 : s3;
    }
    const int drow = (lane >> 4) << 2;
    const int dcol = lane & 15;
    #pragma unroll
    for (int i = 0; i < 4; i++) {
        #pragma unroll
        for (int j = 0; j < NJ; j++) {
            int n = col0 + wc + j * 16 + dcol;
            if (n >= N) continue;
            float bv = bias ? bias[n] : 0.f;
            #pragma unroll
            for (int r = 0; r < 4; r++) {
                int m = row0 + wr + i * 16 + drow + r;
                float v = acc[i][j][r];
                if (MODE == MODE_PROJ) {
                    v += bv;
                    if (n < DI) outf[(size_t)m * DI + n] = v;               // h raw
                    else        outh[(size_t)m * DI + (n - DI)] = (bf16)v;  // gate raw bf16
                } else if (MODE == MODE_XPROJ) {
                    outf[(size_t)blockIdx.z * (BLM * 160) + (size_t)m * 160 + n] = v;
                } else if (MODE == MODE_DT) {
                    outf[(size_t)m * DI + n] = softplusf_(v + bv);          // dt ready
                } else { // MODE_OUT: plain per-slice partial
                    oslice[(size_t)m * HH + n] = v;
                }
            }
        }
    }
}

// sum 16 xproj slices -> sp fp32; cols<128 also -> ts bf16
__global__ __launch_bounds__(256) void reduce_sp(
    const float* __restrict__ spS, float* __restrict__ sp_f, bf16* __restrict__ ts_b)
{
    int i = blockIdx.x * 256 + threadIdx.x;     // 40960 float4 groups
    int row = i / 40, c4 = (i % 40) * 4;
    float4 s = make_float4(0.f, 0.f, 0.f, 0.f);
    #pragma unroll
    for (int z = 0; z < ZXP; z++) {
        float4 v = *(const float4*)&spS[(size_t)z * (BLM * 160) + (size_t)row * 160 + c4];
        s.x += v.x; s.y += v.y; s.z += v.z; s.w += v.w;
    }
    *(float4*)&sp_f[(size_t)row * 160 + c4] = s;
    if (c4 < RR) {
        uint2 o; o.x = bfpack(s.x, s.y); o.y = bfpack(s.z, s.w);
        *(uint2*)&ts_b[(size_t)row * RR + c4] = o;
    }
}

// sum 4 out slices + bias -> d_out fp32
__global__ __launch_bounds__(256) void reduce_out(
    const float* __restrict__ s0, const float* __restrict__ s1,
    const float* __restrict__ s2, const float* __restrict__ s3,
    const float* __restrict__ bias, float* __restrict__ out)
{
    int i = blockIdx.x * 256 + threadIdx.x;     // 524288 float4 groups
    int c4 = (i & 511) << 2;
    float4 a = ((const float4*)s0)[i];
    float4 b = ((const float4*)s1)[i];
    float4 c = ((const float4*)s2)[i];
    float4 d = ((const float4*)s3)[i];
    float4 bv = *(const float4*)&bias[c4];
    float4 r;
    r.x = a.x + b.x + c.x + d.x + bv.x;
    r.y = a.y + b.y + c.y + d.y + bv.y;
    r.z = a.z + b.z + c.z + d.z + bv.z;
    r.w = a.w + b.w + c.w + d.w + bv.w;
    ((float4*)out)[i] = r;
}

// depthwise causal conv K=4 + silu; fp32 in, bf16 out
__global__ __launch_bounds__(256) void conv_silu(
    const float* __restrict__ h, const float* __restrict__ conv_w,
    const float* __restrict__ conv_b, bf16* __restrict__ hs_b)
{
    int idx = blockIdx.x * 256 + threadIdx.x;
    int d = idx & (DI - 1);
    int l = (idx >> 12) & (LL - 1);
    float acc = conv_b[d];
    #pragma unroll
    for (int k = 0; k < KK; k++) {
        int ls = l - (KK - 1) + k;
        if (ls >= 0) acc += h[(size_t)idx + (size_t)(ls - l) * DI] * conv_w[d * KK + k];
    }
    float s = acc * sigmoidf_(acc);
    hs_b[idx] = (bf16)s;
}

// Chunked scan pass 1: per (b,d,chunk) thread; dt already softplus'ed.
__global__ __launch_bounds__(256) void scan_part1(
    const float* __restrict__ dtr, const float* __restrict__ sp,
    const bf16* __restrict__ hs_b, const float* __restrict__ A_log,
    float* __restrict__ P_ws, float* __restrict__ S_ws)
{
    int bid = blockIdx.x;
    int c  = bid & (CN - 1);
    int db = (bid >> 4) & (DI / 256 - 1);
    int b  = bid >> 8;
    int d  = db * 256 + threadIdx.x;

    float A[NST], P[NST], S[NST];
    #pragma unroll
    for (int n = 0; n < NST; n++) {
        A[n] = -__expf(A_log[d * NST + n]);
        P[n] = 1.f; S[n] = 0.f;
    }
    const float* spb = sp + (size_t)b * LL * 160;
    size_t base = (size_t)b * LL * DI + d;
    for (int l = c * LC; l < (c + 1) * LC; l++) {
        size_t off = base + (size_t)l * DI;
        float dtv = dtr[off];
        float hsv = (float)hs_b[off];
        float dh = dtv * hsv;
        #pragma unroll
        for (int n = 0; n < NST; n++) {
            float a  = __expf(dtv * A[n]);
            float Bn = spb[l * 160 + RR + n];
            S[n] = a * S[n] + dh * Bn;
            P[n] *= a;
        }
    }
    size_t o = ((size_t)((b * CN + c) * DI) + d) * NST;
    #pragma unroll
    for (int q = 0; q < 4; q++) {
        *(float4*)&P_ws[o + q * 4] = make_float4(P[q*4], P[q*4+1], P[q*4+2], P[q*4+3]);
        *(float4*)&S_ws[o + q * 4] = make_float4(S[q*4], S[q*4+1], S[q*4+2], S[q*4+3]);
    }
}

// Pass 2: rebuild chunk-initial state, local scan, silu(gate) inline, emit y bf16.
__global__ __launch_bounds__(256) void scan_part2(
    const float* __restrict__ dtr, const float* __restrict__ sp,
    const bf16* __restrict__ hs_b, const bf16* __restrict__ g_b,
    const float* __restrict__ A_log, const float* __restrict__ Dv,
    const float* __restrict__ P_ws, const float* __restrict__ S_ws,
    bf16* __restrict__ y_b)
{
    int bid = blockIdx.x;
    int c  = bid & (CN - 1);
    int db = (bid >> 4) & (DI / 256 - 1);
    int b  = bid >> 8;
    int d  = db * 256 + threadIdx.x;

    float s[NST];
    #pragma unroll
    for (int n = 0; n < NST; n++) s[n] = 0.f;
    for (int j = 0; j < c; j++) {
        size_t o = ((size_t)((b * CN + j) * DI) + d) * NST;
        #pragma unroll
        for (int q = 0; q < 4; q++) {
            float4 Pq = *(const float4*)&P_ws[o + q * 4];
            float4 Sq = *(const float4*)&S_ws[o + q * 4];
            s[q*4+0] = Pq.x * s[q*4+0] + Sq.x;
            s[q*4+1] = Pq.y * s[q*4+1] + Sq.y;
            s[q*4+2] = Pq.z * s[q*4+2] + Sq.z;
            s[q*4+3] = Pq.w * s[q*4+3] + Sq.w;
        }
    }

    float A[NST];
    #pragma unroll
    for (int n = 0; n < NST; n++) A[n] = -__expf(A_log[d * NST + n]);
    float Dd = Dv[d];

    const float* spb = sp + (size_t)b * LL * 160;
    size_t base = (size_t)b * LL * DI + d;
    for (int l = c * LC; l < (c + 1) * LC; l++) {
        size_t off = base + (size_t)l * DI;
        float dtv = dtr[off];
        float hsv = (float)hs_b[off];
        float dh = dtv * hsv;
        float y = 0.f;
        #pragma unroll
        for (int n = 0; n < NST; n++) {
            float a  = __expf(dtv * A[n]);
            float Bn = spb[l * 160 + RR + n];
            float Cn = spb[l * 160 + RR + NST + n];
            s[n] = a * s[n] + dh * Bn;
            y += s[n] * Cn;
        }
        float gv = (float)g_b[off];
        y_b[off] = (bf16)((y + hsv * Dd) * (gv * sigmoidf_(gv)));
    }
}

extern "C" void kernel_launch(void* const* d_in, const int* in_sizes, int n_in,
                              void* d_out, int out_size, void* d_ws, size_t ws_size,
                              hipStream_t stream)
{
    const float* x       = (const float*)d_in[0];
    const float* in_w    = (const float*)d_in[1];
    const float* in_b    = (const float*)d_in[2];
    const float* conv_w  = (const float*)d_in[3];
    const float* conv_b  = (const float*)d_in[4];
    const float* xproj_w = (const float*)d_in[5];
    const float* dt_w    = (const float*)d_in[6];
    const float* dt_b    = (const float*)d_in[7];
    const float* A_log   = (const float*)d_in[8];
    const float* Dv      = (const float*)d_in[9];
    const float* out_w   = (const float*)d_in[10];
    const float* out_b   = (const float*)d_in[11];
    float* out = (float*)d_out;

    // Overlay layout, 67.2 MB total (proven budget 68 MB).
    // [0,32):   in_w_b (D0-proj) | spS 10.5 (xproj-reduce) | P[0,8)+S[8,16) (scan) | oS1[0,8)
    // [16,24):  y_b (scan2-outgemm)    [24,32): oS0
    // [32,48):  h (proj-conv) / dt (dtgemm-scan2) / ow_b (cvt-outgemm)
    // [48,56):  g_b (proj-scan2) | oS2     [56,64): hs_b (conv-scan2) | oS3
    // [64,~67): sp_f, ts_b, xw_b, dtw_b
    char* ws = (char*)d_ws;
    const size_t MB = 1u << 20;
    bf16*  in_w_b = (bf16*)(ws);
    float* spS    = (float*)(ws);
    float* P_ws   = (float*)(ws);
    float* S_ws   = (float*)(ws + 8 * MB);
    bf16*  y_b    = (bf16*)(ws + 16 * MB);
    float* oS0    = (float*)(ws + 24 * MB);
    float* oS1    = (float*)(ws);
    float* h_dt   = (float*)(ws + 32 * MB);
    bf16*  ow_b   = (bf16*)(ws + 32 * MB);
    float* oS2    = (float*)(ws + 48 * MB);
    bf16*  g_b    = (bf16*)(ws + 48 * MB);
    float* oS3    = (float*)(ws + 56 * MB);
    bf16*  hs_b   = (bf16*)(ws + 56 * MB);
    char* p = ws + 64 * MB;
    float* sp_f = (float*)p; p += (size_t)BLM * 160 * 4;        // 0.625 MB
    bf16*  ts_b = (bf16*)p;  p += (size_t)BLM * RR * 2;         // 0.25 MB
    bf16*  xw_b = (bf16*)p;  p += (size_t)(RR + 2 * NST) * DI * 2;  // 1.25 MB
    bf16*  dtw_b= (bf16*)p;  p += (size_t)DI * RR * 2;          // 1 MB

    // D0: convert weights (x stays fp32; staged in-GEMM)
    cvt_f32_bf16<<<512, 256, 0, stream>>>(in_w, in_w_b, 2 * DI * HH / 4);
    cvt_f32_bf16<<<640, 256, 0, stream>>>(xproj_w, xw_b, (RR + 2 * NST) * DI / 4);
    cvt_f32_bf16<<<512, 256, 0, stream>>>(dt_w, dtw_b, DI * RR / 4);
    // D1: proj = x @ in_w^T + in_b -> h fp32, gate bf16   (A from fp32)
    gemm_bf16<128, MODE_PROJ, true><<<dim3((2 * DI) / 128, BLM / 128, 1), 256, 0, stream>>>(
        x, in_w_b, 2 * DI, HH, HH, HH, in_b, h_dt, g_b, nullptr, nullptr, nullptr, nullptr);
    // D2: conv + silu -> hs bf16
    conv_silu<<<(BLM * DI) / 256, 256, 0, stream>>>(h_dt, conv_w, conv_b, hs_b);
    // D3: sp partials (BM=64, split-K=16, plain stores)
    gemm_bf16<64, MODE_XPROJ, false><<<dim3(2, BLM / 64, ZXP), 256, 0, stream>>>(
        hs_b, xw_b, RR + 2 * NST, DI, DI, DI, nullptr, spS, nullptr, nullptr, nullptr, nullptr, nullptr);
    // D4: reduce slices -> sp fp32 + ts bf16
    reduce_sp<<<160, 256, 0, stream>>>(spS, sp_f, ts_b);
    // D5: dt = softplus(ts @ dt_w^T + dt_b)
    gemm_bf16<64, MODE_DT, false><<<dim3(DI / 128, BLM / 64, 1), 256, 0, stream>>>(
        ts_b, dtw_b, DI, RR, RR, RR, dt_b, h_dt, nullptr, nullptr, nullptr, nullptr, nullptr);
    // D6-D7: chunked scan -> y bf16
    scan_part1<<<BB * (DI / 256) * CN, 256, 0, stream>>>(
        h_dt, sp_f, hs_b, A_log, P_ws, S_ws);
    scan_part2<<<BB * (DI / 256) * CN, 256, 0, stream>>>(
        h_dt, sp_f, hs_b, g_b, A_log, Dv, P_ws, S_ws, y_b);
    // D8: convert out_w (over dead dt region)
    cvt_f32_bf16<<<512, 256, 0, stream>>>(out_w, ow_b, HH * DI / 4);
    // D9: out partials (BM=128, split-K=4, plain per-slice stores)
    gemm_bf16<128, MODE_OUT, false><<<dim3(HH / 128, BLM / 128, ZOUT), 256, 0, stream>>>(
        y_b, ow_b, HH, DI, DI, DI, nullptr, nullptr, nullptr, oS0, oS1, oS2, oS3);
    // D10: reduce + bias -> d_out
    reduce_out<<<2048, 256, 0, stream>>>(oS0, oS1, oS2, oS3, out_b, out);
}

// Round 6
// 375.070 us; speedup vs baseline: 2.9620x; 1.0853x over previous
//
#include <hip/hip_runtime.h>
#include <hip/hip_bf16.h>

typedef __hip_bfloat16 bf16;
typedef short bf16x8 __attribute__((ext_vector_type(8)));
typedef float f32x4 __attribute__((ext_vector_type(4)));

#define BB 2
#define LL 512
#define HH 2048
#define DI 4096
#define NST 16
#define KK 4
#define RR 128
#define BLM (BB*LL)   // 1024 rows
#define CN 16         // scan chunks
#define LC (LL/CN)    // 32 steps per chunk
#define ZXP 16        // xproj split-K
#define ZOUT 4        // out split-K

enum { MODE_PROJ = 0, MODE_XPROJ = 1, MODE_DT = 2, MODE_OUT = 3 };

__device__ __forceinline__ float sigmoidf_(float x) { return 1.f / (1.f + __expf(-x)); }
__device__ __forceinline__ float softplusf_(float x) {
    return fmaxf(x, 0.f) + log1pf(__expf(-fabsf(x)));
}
__device__ __forceinline__ unsigned int bfpack(float a, float b) {
    __hip_bfloat162 h = __float22bfloat162_rn(make_float2(a, b));
    union { __hip_bfloat162 h; unsigned int u; } cv; cv.h = h;
    return cv.u;
}

typedef const __attribute__((address_space(1))) unsigned int* gas_t;
typedef __attribute__((address_space(3))) unsigned int* las_t;
__device__ __forceinline__ void gld16(const void* g, void* l) {
    __builtin_amdgcn_global_load_lds((gas_t)g, (las_t)l, 16, 0, 0);
}

__device__ __forceinline__ void cvt_seg(const float* s, bf16* d, int i) {
    float4 v = ((const float4*)s)[i];
    uint2 o; o.x = bfpack(v.x, v.y); o.y = bfpack(v.z, v.w);
    ((uint2*)d)[i] = o;
}

// fused fp32->bf16 for 4 tensors, grid-stride over concatenated float4 ranges
__global__ __launch_bounds__(256) void cvt_all(
    const float* __restrict__ s0, bf16* __restrict__ d0, int n0,
    const float* __restrict__ s1, bf16* __restrict__ d1, int n1,
    const float* __restrict__ s2, bf16* __restrict__ d2, int n2,
    const float* __restrict__ s3, bf16* __restrict__ d3, int n3)
{
    int i = blockIdx.x * 256 + threadIdx.x;
    int stride = gridDim.x * 256;
    int t1 = n0 + n1, t2 = t1 + n2, t3 = t2 + n3;
    for (; i < t3; i += stride) {
        if      (i < n0) cvt_seg(s0, d0, i);
        else if (i < t1) cvt_seg(s1, d1, i - n0);
        else if (i < t2) cvt_seg(s2, d2, i - t1);
        else             cvt_seg(s3, d3, i - t2);
    }
}

// single-tensor fp32 -> bf16
__global__ __launch_bounds__(256) void cvt_f32_bf16(
    const float* __restrict__ src, bf16* __restrict__ dst, int n4)
{
    int i = blockIdx.x * 256 + threadIdx.x;
    int stride = gridDim.x * 256;
    for (; i < n4; i += stride) cvt_seg(src, dst, i);
}

// C = A(M,K;lda)bf16 @ B(N,K;ldb)^T bf16, fp32 accum, global_load_lds staging
// for BOTH operands (m97 pattern). blockIdx.x = COL tile (XCD swizzle),
// blockIdx.y = row tile, blockIdx.z = split-K slice. No atomics.
template<int BM, int MODE>
__global__ __launch_bounds__(256) void gemm_bf16(
    const bf16* __restrict__ A, const bf16* __restrict__ Bw,
    int N, int K, int lda, int ldb,
    const float* __restrict__ bias,
    float* __restrict__ outf, bf16* __restrict__ outh, bf16* __restrict__ outh2,
    float* __restrict__ s0, float* __restrict__ s1,
    float* __restrict__ s2, float* __restrict__ s3)
{
    __shared__ short sA[BM * 32];
    __shared__ short sB[128 * 32];
    const int tid = threadIdx.x;
    const int col0 = blockIdx.x * 128;
    const int row0 = blockIdx.y * BM;
    const int wave = tid >> 6;
    const int lane = tid & 63;
    constexpr int NJ = (BM == 128) ? 4 : 2;
    const int wr = (BM == 128) ? ((wave >> 1) * 64) : 0;
    const int wc = (BM == 128) ? ((wave & 1) * 64) : (wave * 32);
    const int lr = lane & 15;
    const int kq = (lane >> 4) << 3;

    const int kpb = K / gridDim.z;
    const int kbeg = blockIdx.z * kpb;
    const int kend = kbeg + kpb;

    const int r0 = tid >> 2;            // 0..63
    const int kc = (tid & 3) << 3;      // 0,8,16,24

    f32x4 acc[4][NJ] = {};

    for (int k0 = kbeg; k0 < kend; k0 += 32) {
        #pragma unroll
        for (int p = 0; p < BM / 64; p++) {
            int r = r0 + p * 64;
            gld16(A + (size_t)(row0 + r) * lda + k0 + kc, &sA[r * 32 + kc]);
        }
        #pragma unroll
        for (int p = 0; p < 2; p++) {
            int rr = r0 + p * 64;
            int nb = col0 + rr; if (nb > N - 1) nb = N - 1;   // clamp (epilogue guards)
            gld16(Bw + (size_t)nb * ldb + k0 + kc, &sB[rr * 32 + kc]);
        }
        __syncthreads();
        bf16x8 af[4], bfr[NJ];
        #pragma unroll
        for (int i = 0; i < 4; i++)
            af[i] = *(const bf16x8*)(&sA[(wr + i * 16 + lr) * 32 + kq]);
        #pragma unroll
        for (int j = 0; j < NJ; j++)
            bfr[j] = *(const bf16x8*)(&sB[(wc + j * 16 + lr) * 32 + kq]);
        #pragma unroll
        for (int i = 0; i < 4; i++)
            #pragma unroll
            for (int j = 0; j < NJ; j++)
                acc[i][j] = __builtin_amdgcn_mfma_f32_16x16x32_bf16(af[i], bfr[j], acc[i][j], 0, 0, 0);
        __syncthreads();
    }

    float* oslice = outf;
    if (MODE == MODE_OUT) {
        int z = blockIdx.z;
        oslice = (z == 0) ? s0 : (z == 1) ? s1 : (z == 2) ? s2 : s3;
    }
    const int drow = (lane >> 4) << 2;
    const int dcol = lane & 15;
    #pragma unroll
    for (int i = 0; i < 4; i++) {
        #pragma unroll
        for (int j = 0; j < NJ; j++) {
            int n = col0 + wc + j * 16 + dcol;
            if (n >= N) continue;
            float bv = bias ? bias[n] : 0.f;
            #pragma unroll
            for (int r = 0; r < 4; r++) {
                int m = row0 + wr + i * 16 + drow + r;
                float v = acc[i][j][r];
                if (MODE == MODE_PROJ) {
                    v += bv;
                    if (n < DI) outh2[(size_t)m * DI + n] = (bf16)v;         // h bf16
                    else        outh[(size_t)m * DI + (n - DI)] = (bf16)v;   // gate bf16
                } else if (MODE == MODE_XPROJ) {
                    outf[(size_t)blockIdx.z * (BLM * 160) + (size_t)m * 160 + n] = v;
                } else if (MODE == MODE_DT) {
                    outf[(size_t)m * DI + n] = softplusf_(v + bv);           // dt ready
                } else { // MODE_OUT: plain per-slice partial
                    oslice[(size_t)m * HH + n] = v;
                }
            }
        }
    }
}

// sum 16 xproj slices -> sp fp32; cols<128 also -> ts bf16
__global__ __launch_bounds__(256) void reduce_sp(
    const float* __restrict__ spS, float* __restrict__ sp_f, bf16* __restrict__ ts_b)
{
    int i = blockIdx.x * 256 + threadIdx.x;     // 40960 float4 groups
    int row = i / 40, c4 = (i % 40) * 4;
    float4 s = make_float4(0.f, 0.f, 0.f, 0.f);
    #pragma unroll
    for (int z = 0; z < ZXP; z++) {
        float4 v = *(const float4*)&spS[(size_t)z * (BLM * 160) + (size_t)row * 160 + c4];
        s.x += v.x; s.y += v.y; s.z += v.z; s.w += v.w;
    }
    *(float4*)&sp_f[(size_t)row * 160 + c4] = s;
    if (c4 < RR) {
        uint2 o; o.x = bfpack(s.x, s.y); o.y = bfpack(s.z, s.w);
        *(uint2*)&ts_b[(size_t)row * RR + c4] = o;
    }
}

// sum 4 out slices + bias -> d_out fp32
__global__ __launch_bounds__(256) void reduce_out(
    const float* __restrict__ s0, const float* __restrict__ s1,
    const float* __restrict__ s2, const float* __restrict__ s3,
    const float* __restrict__ bias, float* __restrict__ out)
{
    int i = blockIdx.x * 256 + threadIdx.x;     // 524288 float4 groups
    int c4 = (i & 511) << 2;
    float4 a = ((const float4*)s0)[i];
    float4 b = ((const float4*)s1)[i];
    float4 c = ((const float4*)s2)[i];
    float4 d = ((const float4*)s3)[i];
    float4 bv = *(const float4*)&bias[c4];
    float4 r;
    r.x = a.x + b.x + c.x + d.x + bv.x;
    r.y = a.y + b.y + c.y + d.y + bv.y;
    r.z = a.z + b.z + c.z + d.z + bv.z;
    r.w = a.w + b.w + c.w + d.w + bv.w;
    ((float4*)out)[i] = r;
}

// depthwise causal conv K=4 + silu; bf16 h in (fp32 math), bf16 out
__global__ __launch_bounds__(256) void conv_silu(
    const bf16* __restrict__ h, const float* __restrict__ conv_w,
    const float* __restrict__ conv_b, bf16* __restrict__ hs_b)
{
    int idx = blockIdx.x * 256 + threadIdx.x;
    int d = idx & (DI - 1);
    int l = (idx >> 12) & (LL - 1);
    float acc = conv_b[d];
    #pragma unroll
    for (int k = 0; k < KK; k++) {
        int ls = l - (KK - 1) + k;
        if (ls >= 0) acc += (float)h[(size_t)idx + (size_t)(ls - l) * DI] * conv_w[d * KK + k];
    }
    float s = acc * sigmoidf_(acc);
    hs_b[idx] = (bf16)s;
}

// Chunked scan pass 1: per (b,d,chunk) thread; dt already softplus'ed.
__global__ __launch_bounds__(256) void scan_part1(
    const float* __restrict__ dtr, const float* __restrict__ sp,
    const bf16* __restrict__ hs_b, const float* __restrict__ A_log,
    float* __restrict__ P_ws, float* __restrict__ S_ws)
{
    int bid = blockIdx.x;
    int c  = bid & (CN - 1);
    int db = (bid >> 4) & (DI / 256 - 1);
    int b  = bid >> 8;
    int d  = db * 256 + threadIdx.x;

    float A[NST], P[NST], S[NST];
    #pragma unroll
    for (int n = 0; n < NST; n++) {
        A[n] = -__expf(A_log[d * NST + n]);
        P[n] = 1.f; S[n] = 0.f;
    }
    const float* spb = sp + (size_t)b * LL * 160;
    size_t base = (size_t)b * LL * DI + d;
    for (int l = c * LC; l < (c + 1) * LC; l++) {
        size_t off = base + (size_t)l * DI;
        float dtv = dtr[off];
        float hsv = (float)hs_b[off];
        float dh = dtv * hsv;
        #pragma unroll
        for (int n = 0; n < NST; n++) {
            float a  = __expf(dtv * A[n]);
            float Bn = spb[l * 160 + RR + n];
            S[n] = a * S[n] + dh * Bn;
            P[n] *= a;
        }
    }
    size_t o = ((size_t)((b * CN + c) * DI) + d) * NST;
    #pragma unroll
    for (int q = 0; q < 4; q++) {
        *(float4*)&P_ws[o + q * 4] = make_float4(P[q*4], P[q*4+1], P[q*4+2], P[q*4+3]);
        *(float4*)&S_ws[o + q * 4] = make_float4(S[q*4], S[q*4+1], S[q*4+2], S[q*4+3]);
    }
}

// Pass 2: rebuild chunk-initial state, local scan, silu(gate) inline, emit y bf16.
__global__ __launch_bounds__(256) void scan_part2(
    const float* __restrict__ dtr, const float* __restrict__ sp,
    const bf16* __restrict__ hs_b, const bf16* __restrict__ g_b,
    const float* __restrict__ A_log, const float* __restrict__ Dv,
    const float* __restrict__ P_ws, const float* __restrict__ S_ws,
    bf16* __restrict__ y_b)
{
    int bid = blockIdx.x;
    int c  = bid & (CN - 1);
    int db = (bid >> 4) & (DI / 256 - 1);
    int b  = bid >> 8;
    int d  = db * 256 + threadIdx.x;

    float s[NST];
    #pragma unroll
    for (int n = 0; n < NST; n++) s[n] = 0.f;
    for (int j = 0; j < c; j++) {
        size_t o = ((size_t)((b * CN + j) * DI) + d) * NST;
        #pragma unroll
        for (int q = 0; q < 4; q++) {
            float4 Pq = *(const float4*)&P_ws[o + q * 4];
            float4 Sq = *(const float4*)&S_ws[o + q * 4];
            s[q*4+0] = Pq.x * s[q*4+0] + Sq.x;
            s[q*4+1] = Pq.y * s[q*4+1] + Sq.y;
            s[q*4+2] = Pq.z * s[q*4+2] + Sq.z;
            s[q*4+3] = Pq.w * s[q*4+3] + Sq.w;
        }
    }

    float A[NST];
    #pragma unroll
    for (int n = 0; n < NST; n++) A[n] = -__expf(A_log[d * NST + n]);
    float Dd = Dv[d];

    const float* spb = sp + (size_t)b * LL * 160;
    size_t base = (size_t)b * LL * DI + d;
    for (int l = c * LC; l < (c + 1) * LC; l++) {
        size_t off = base + (size_t)l * DI;
        float dtv = dtr[off];
        float hsv = (float)hs_b[off];
        float dh = dtv * hsv;
        float y = 0.f;
        #pragma unroll
        for (int n = 0; n < NST; n++) {
            float a  = __expf(dtv * A[n]);
            float Bn = spb[l * 160 + RR + n];
            float Cn = spb[l * 160 + RR + NST + n];
            s[n] = a * s[n] + dh * Bn;
            y += s[n] * Cn;
        }
        float gv = (float)g_b[off];
        y_b[off] = (bf16)((y + hsv * Dd) * (gv * sigmoidf_(gv)));
    }
}

extern "C" void kernel_launch(void* const* d_in, const int* in_sizes, int n_in,
                              void* d_out, int out_size, void* d_ws, size_t ws_size,
                              hipStream_t stream)
{
    const float* x       = (const float*)d_in[0];
    const float* in_w    = (const float*)d_in[1];
    const float* in_b    = (const float*)d_in[2];
    const float* conv_w  = (const float*)d_in[3];
    const float* conv_b  = (const float*)d_in[4];
    const float* xproj_w = (const float*)d_in[5];
    const float* dt_w    = (const float*)d_in[6];
    const float* dt_b    = (const float*)d_in[7];
    const float* A_log   = (const float*)d_in[8];
    const float* Dv      = (const float*)d_in[9];
    const float* out_w   = (const float*)d_in[10];
    const float* out_b   = (const float*)d_in[11];
    float* out = (float*)d_out;

    // Overlay layout, 67.2 MB peak (same as proven round-5 footprint).
    // [0,4):   x_b (D0-D1)       [0,16): spS 10.5 (D3-D4) / P[0,8)+S[8,16) (D6-D7) / oS1[0,8) (D9)
    // [16,48): in_w_b (D0-D1); then [16,24) y_b (D7-D9), [24,32) hs_b (D2-D7)->oS0 (D9),
    //          [32,48) dt fp32 (D5-D7) -> ow_b (D8-D9)
    // [48,56): h_b (D1-D2) -> oS2 (D9)     [56,64): g_b (D1-D7) -> oS3 (D9)
    // [64,~67.2): sp_f, ts_b, xw_b, dtw_b
    char* ws = (char*)d_ws;
    const size_t MB = 1u << 20;
    bf16*  x_b    = (bf16*)(ws);
    float* spS    = (float*)(ws);
    float* P_ws   = (float*)(ws);
    float* S_ws   = (float*)(ws + 8 * MB);
    float* oS1    = (float*)(ws);
    bf16*  in_w_b = (bf16*)(ws + 16 * MB);
    bf16*  y_b    = (bf16*)(ws + 16 * MB);
    bf16*  hs_b   = (bf16*)(ws + 24 * MB);
    float* oS0    = (float*)(ws + 24 * MB);
    float* dt_f   = (float*)(ws + 32 * MB);
    bf16*  ow_b   = (bf16*)(ws + 32 * MB);
    bf16*  h_b    = (bf16*)(ws + 48 * MB);
    float* oS2    = (float*)(ws + 48 * MB);
    bf16*  g_b    = (bf16*)(ws + 56 * MB);
    float* oS3    = (float*)(ws + 56 * MB);
    char* p = ws + 64 * MB;
    float* sp_f = (float*)p; p += (size_t)BLM * 160 * 4;        // 0.625 MB
    bf16*  ts_b = (bf16*)p;  p += (size_t)BLM * RR * 2;         // 0.25 MB
    bf16*  xw_b = (bf16*)p;  p += (size_t)(RR + 2 * NST) * DI * 2;  // 1.25 MB
    bf16*  dtw_b= (bf16*)p;  p += (size_t)DI * RR * 2;          // 1 MB

    // D0: fused convert x + in_w + xproj_w + dt_w to bf16
    cvt_all<<<2048, 256, 0, stream>>>(
        x, x_b, BLM * HH / 4,
        in_w, in_w_b, 2 * DI * HH / 4,
        xproj_w, xw_b, (RR + 2 * NST) * DI / 4,
        dt_w, dtw_b, DI * RR / 4);
    // D1: proj = x @ in_w^T + in_b -> h bf16, gate bf16 (both operands gld16)
    gemm_bf16<128, MODE_PROJ><<<dim3((2 * DI) / 128, BLM / 128, 1), 256, 0, stream>>>(
        x_b, in_w_b, 2 * DI, HH, HH, HH, in_b, nullptr, g_b, h_b,
        nullptr, nullptr, nullptr, nullptr);
    // D2: conv + silu -> hs bf16
    conv_silu<<<(BLM * DI) / 256, 256, 0, stream>>>(h_b, conv_w, conv_b, hs_b);
    // D3: sp partials (BM=64, split-K=16, plain stores)
    gemm_bf16<64, MODE_XPROJ><<<dim3(2, BLM / 64, ZXP), 256, 0, stream>>>(
        hs_b, xw_b, RR + 2 * NST, DI, DI, DI, nullptr, spS, nullptr, nullptr,
        nullptr, nullptr, nullptr, nullptr);
    // D4: reduce slices -> sp fp32 + ts bf16
    reduce_sp<<<160, 256, 0, stream>>>(spS, sp_f, ts_b);
    // D5: dt = softplus(ts @ dt_w^T + dt_b)
    gemm_bf16<64, MODE_DT><<<dim3(DI / 128, BLM / 64, 1), 256, 0, stream>>>(
        ts_b, dtw_b, DI, RR, RR, RR, dt_b, dt_f, nullptr, nullptr,
        nullptr, nullptr, nullptr, nullptr);
    // D6-D7: chunked scan -> y bf16
    scan_part1<<<BB * (DI / 256) * CN, 256, 0, stream>>>(
        dt_f, sp_f, hs_b, A_log, P_ws, S_ws);
    scan_part2<<<BB * (DI / 256) * CN, 256, 0, stream>>>(
        dt_f, sp_f, hs_b, g_b, A_log, Dv, P_ws, S_ws, y_b);
    // D8: convert out_w (over dead dt region)
    cvt_f32_bf16<<<512, 256, 0, stream>>>(out_w, ow_b, HH * DI / 4);
    // D9: out partials (BM=128, split-K=4, plain per-slice stores)
    gemm_bf16<128, MODE_OUT><<<dim3(HH / 128, BLM / 128, ZOUT), 256, 0, stream>>>(
        y_b, ow_b, HH, DI, DI, DI, nullptr, nullptr, nullptr, nullptr,
        oS0, oS1, oS2, oS3);
    // D10: reduce + bias -> d_out
    reduce_out<<<2048, 256, 0, stream>>>(oS0, oS1, oS2, oS3, out_b, out);
}

// Round 9
// 368.313 us; speedup vs baseline: 3.0163x; 1.0183x over previous
//
#include <hip/hip_runtime.h>
#include <hip/hip_bf16.h>

typedef __hip_bfloat16 bf16;
typedef _Float16 fp16;
typedef short bf16x8 __attribute__((ext_vector_type(8)));
typedef float f32x4 __attribute__((ext_vector_type(4)));
typedef _Float16 half8 __attribute__((ext_vector_type(8)));

#define BB 2
#define LL 512
#define HH 2048
#define DI 4096
#define NST 16
#define KK 4
#define RR 128
#define BLM (BB*LL)   // 1024 rows
#define CN 16         // scan chunks
#define LC (LL/CN)    // 32 steps per chunk
#define ZXP 16        // xproj split-K
#define ZOUT 4        // out split-K

enum { MODE_PROJ = 0, MODE_XPROJ = 1, MODE_DT = 2, MODE_OUT = 3 };

__device__ __forceinline__ float sigmoidf_(float x) { return 1.f / (1.f + __expf(-x)); }
__device__ __forceinline__ float softplusf_(float x) {
    return fmaxf(x, 0.f) + log1pf(__expf(-fabsf(x)));
}
__device__ __forceinline__ unsigned int bfpack(float a, float b) {
    __hip_bfloat162 h = __float22bfloat162_rn(make_float2(a, b));
    union { __hip_bfloat162 h; unsigned int u; } cv; cv.h = h;
    return cv.u;
}

typedef const __attribute__((address_space(1))) unsigned int* gas_t;
typedef __attribute__((address_space(3))) unsigned int* las_t;
__device__ __forceinline__ void gld16(const void* g, void* l) {
    __builtin_amdgcn_global_load_lds((gas_t)g, (las_t)l, 16, 0, 0);
}

__device__ __forceinline__ void cvt_seg(const float* s, bf16* d, int i) {
    float4 v = ((const float4*)s)[i];
    uint2 o; o.x = bfpack(v.x, v.y); o.y = bfpack(v.z, v.w);
    ((uint2*)d)[i] = o;
}

// fused fp32->bf16 for 4 tensors, grid-stride over concatenated float4 ranges
__global__ __launch_bounds__(256) void cvt_all(
    const float* __restrict__ s0, bf16* __restrict__ d0, int n0,
    const float* __restrict__ s1, bf16* __restrict__ d1, int n1,
    const float* __restrict__ s2, bf16* __restrict__ d2, int n2,
    const float* __restrict__ s3, bf16* __restrict__ d3, int n3)
{
    int i = blockIdx.x * 256 + threadIdx.x;
    int stride = gridDim.x * 256;
    int t1 = n0 + n1, t2 = t1 + n2, t3 = t2 + n3;
    for (; i < t3; i += stride) {
        if      (i < n0) cvt_seg(s0, d0, i);
        else if (i < t1) cvt_seg(s1, d1, i - n0);
        else if (i < t2) cvt_seg(s2, d2, i - t1);
        else             cvt_seg(s3, d3, i - t2);
    }
}

// single-tensor fp32 -> bf16
__global__ __launch_bounds__(256) void cvt_f32_bf16(
    const float* __restrict__ src, bf16* __restrict__ dst, int n4)
{
    int i = blockIdx.x * 256 + threadIdx.x;
    int stride = gridDim.x * 256;
    for (; i < n4; i += stride) cvt_seg(src, dst, i);
}

// C = A(M,K;lda)bf16 @ B(N,K;ldb)^T bf16, fp32 accum, global_load_lds staging.
// blockIdx.x = COL tile (XCD swizzle), blockIdx.y = row tile, blockIdx.z = split-K.
// BN=64 variants give 1024-block grids (4 blocks/CU) for cross-block barrier overlap.
template<int BM, int BN, int MODE>
__global__ __launch_bounds__(256) void gemm_bf16(
    const bf16* __restrict__ A, const bf16* __restrict__ Bw,
    int N, int K, int lda, int ldb,
    const float* __restrict__ bias,
    float* __restrict__ outf, bf16* __restrict__ outh, bf16* __restrict__ outh2,
    fp16* __restrict__ s0, fp16* __restrict__ s1,
    fp16* __restrict__ s2, fp16* __restrict__ s3)
{
    __shared__ short sA[BM * 32];
    __shared__ short sB[BN * 32];
    const int tid = threadIdx.x;
    const int col0 = blockIdx.x * BN;
    const int row0 = blockIdx.y * BM;
    const int wave = tid >> 6;
    const int lane = tid & 63;
    constexpr int NJ = (BM == 64 || BN == 64) ? 2 : 4;
    const int wr = (BM == 128) ? ((wave >> 1) * 64) : 0;
    const int wc = (BM == 64) ? (wave * 32) : ((wave & 1) * (BN / 2));
    const int lr = lane & 15;
    const int kq = (lane >> 4) << 3;

    const int kpb = K / gridDim.z;
    const int kbeg = blockIdx.z * kpb;
    const int kend = kbeg + kpb;

    const int r0 = tid >> 2;            // 0..63
    const int kc = (tid & 3) << 3;      // 0,8,16,24

    f32x4 acc[4][NJ] = {};

    for (int k0 = kbeg; k0 < kend; k0 += 32) {
        #pragma unroll
        for (int p = 0; p < BM / 64; p++) {
            int r = r0 + p * 64;
            gld16(A + (size_t)(row0 + r) * lda + k0 + kc, &sA[r * 32 + kc]);
        }
        #pragma unroll
        for (int p = 0; p < BN / 64; p++) {
            int rr = r0 + p * 64;
            int nb = col0 + rr; if (nb > N - 1) nb = N - 1;   // clamp (epilogue guards)
            gld16(Bw + (size_t)nb * ldb + k0 + kc, &sB[rr * 32 + kc]);
        }
        __syncthreads();
        bf16x8 af[4], bfr[NJ];
        #pragma unroll
        for (int i = 0; i < 4; i++)
            af[i] = *(const bf16x8*)(&sA[(wr + i * 16 + lr) * 32 + kq]);
        #pragma unroll
        for (int j = 0; j < NJ; j++)
            bfr[j] = *(const bf16x8*)(&sB[(wc + j * 16 + lr) * 32 + kq]);
        #pragma unroll
        for (int i = 0; i < 4; i++)
            #pragma unroll
            for (int j = 0; j < NJ; j++)
                acc[i][j] = __builtin_amdgcn_mfma_f32_16x16x32_bf16(af[i], bfr[j], acc[i][j], 0, 0, 0);
        __syncthreads();
    }

    fp16* oslice = nullptr;
    if (MODE == MODE_OUT) {
        int z = blockIdx.z;
        oslice = (z == 0) ? s0 : (z == 1) ? s1 : (z == 2) ? s2 : s3;
    }
    const int drow = (lane >> 4) << 2;
    const int dcol = lane & 15;
    #pragma unroll
    for (int i = 0; i < 4; i++) {
        #pragma unroll
        for (int j = 0; j < NJ; j++) {
            int n = col0 + wc + j * 16 + dcol;
            if (n >= N) continue;
            float bv = bias ? bias[n] : 0.f;
            #pragma unroll
            for (int r = 0; r < 4; r++) {
                int m = row0 + wr + i * 16 + drow + r;
                float v = acc[i][j][r];
                if (MODE == MODE_PROJ) {
                    v += bv;
                    if (n < DI) outh2[(size_t)m * DI + n] = (bf16)v;         // h bf16
                    else        outh[(size_t)m * DI + (n - DI)] = (bf16)v;   // gate bf16
                } else if (MODE == MODE_XPROJ) {
                    outf[(size_t)blockIdx.z * (BLM * 160) + (size_t)m * 160 + n] = v;
                } else if (MODE == MODE_DT) {
                    outf[(size_t)m * DI + n] = softplusf_(v + bv);           // dt ready
                } else { // MODE_OUT: fp16 per-slice partial
                    oslice[(size_t)m * HH + n] = (fp16)v;
                }
            }
        }
    }
}

// sum 16 xproj slices -> sp fp32; cols<128 also -> ts bf16
__global__ __launch_bounds__(256) void reduce_sp(
    const float* __restrict__ spS, float* __restrict__ sp_f, bf16* __restrict__ ts_b)
{
    int i = blockIdx.x * 256 + threadIdx.x;     // 40960 float4 groups
    int row = i / 40, c4 = (i % 40) * 4;
    float4 s = make_float4(0.f, 0.f, 0.f, 0.f);
    #pragma unroll
    for (int z = 0; z < ZXP; z++) {
        float4 v = *(const float4*)&spS[(size_t)z * (BLM * 160) + (size_t)row * 160 + c4];
        s.x += v.x; s.y += v.y; s.z += v.z; s.w += v.w;
    }
    *(float4*)&sp_f[(size_t)row * 160 + c4] = s;
    if (c4 < RR) {
        uint2 o; o.x = bfpack(s.x, s.y); o.y = bfpack(s.z, s.w);
        *(uint2*)&ts_b[(size_t)row * RR + c4] = o;
    }
}

// sum 4 fp16 out slices + bias -> d_out fp32 (8 elems/thread)
__global__ __launch_bounds__(256) void reduce_out(
    const fp16* __restrict__ s0, const fp16* __restrict__ s1,
    const fp16* __restrict__ s2, const fp16* __restrict__ s3,
    const float* __restrict__ bias, float* __restrict__ out)
{
    int i = blockIdx.x * 256 + threadIdx.x;     // 262144 groups of 8
    int c8 = (i & 255) << 3;
    half8 a = ((const half8*)s0)[i];
    half8 b = ((const half8*)s1)[i];
    half8 c = ((const half8*)s2)[i];
    half8 d = ((const half8*)s3)[i];
    float r[8];
    #pragma unroll
    for (int e = 0; e < 8; e++)
        r[e] = (float)a[e] + (float)b[e] + (float)c[e] + (float)d[e] + bias[c8 + e];
    ((float4*)out)[2 * i]     = make_float4(r[0], r[1], r[2], r[3]);
    ((float4*)out)[2 * i + 1] = make_float4(r[4], r[5], r[6], r[7]);
}

// depthwise causal conv K=4 + silu; bf16 h in (fp32 math), bf16 out
__global__ __launch_bounds__(256) void conv_silu(
    const bf16* __restrict__ h, const float* __restrict__ conv_w,
    const float* __restrict__ conv_b, bf16* __restrict__ hs_b)
{
    int idx = blockIdx.x * 256 + threadIdx.x;
    int d = idx & (DI - 1);
    int l = (idx >> 12) & (LL - 1);
    float acc = conv_b[d];
    #pragma unroll
    for (int k = 0; k < KK; k++) {
        int ls = l - (KK - 1) + k;
        if (ls >= 0) acc += (float)h[(size_t)idx + (size_t)(ls - l) * DI] * conv_w[d * KK + k];
    }
    float s = acc * sigmoidf_(acc);
    hs_b[idx] = (bf16)s;
}

// Chunked scan pass 1: per (b,d,chunk) thread; dt already softplus'ed.
__global__ __launch_bounds__(256) void scan_part1(
    const float* __restrict__ dtr, const float* __restrict__ sp,
    const bf16* __restrict__ hs_b, const float* __restrict__ A_log,
    float* __restrict__ P_ws, float* __restrict__ S_ws)
{
    int bid = blockIdx.x;
    int c  = bid & (CN - 1);
    int db = (bid >> 4) & (DI / 256 - 1);
    int b  = bid >> 8;
    int d  = db * 256 + threadIdx.x;

    float A[NST], P[NST], S[NST];
    #pragma unroll
    for (int n = 0; n < NST; n++) {
        A[n] = -__expf(A_log[d * NST + n]);
        P[n] = 1.f; S[n] = 0.f;
    }
    const float* spb = sp + (size_t)b * LL * 160;
    size_t base = (size_t)b * LL * DI + d;
    for (int l = c * LC; l < (c + 1) * LC; l++) {
        size_t off = base + (size_t)l * DI;
        float dtv = dtr[off];
        float hsv = (float)hs_b[off];
        float dh = dtv * hsv;
        #pragma unroll
        for (int n = 0; n < NST; n++) {
            float a  = __expf(dtv * A[n]);
            float Bn = spb[l * 160 + RR + n];
            S[n] = a * S[n] + dh * Bn;
            P[n] *= a;
        }
    }
    size_t o = ((size_t)((b * CN + c) * DI) + d) * NST;
    #pragma unroll
    for (int q = 0; q < 4; q++) {
        *(float4*)&P_ws[o + q * 4] = make_float4(P[q*4], P[q*4+1], P[q*4+2], P[q*4+3]);
        *(float4*)&S_ws[o + q * 4] = make_float4(S[q*4], S[q*4+1], S[q*4+2], S[q*4+3]);
    }
}

// Pass 2: rebuild chunk-initial state, local scan, silu(gate) inline, emit y bf16.
__global__ __launch_bounds__(256) void scan_part2(
    const float* __restrict__ dtr, const float* __restrict__ sp,
    const bf16* __restrict__ hs_b, const bf16* __restrict__ g_b,
    const float* __restrict__ A_log, const float* __restrict__ Dv,
    const float* __restrict__ P_ws, const float* __restrict__ S_ws,
    bf16* __restrict__ y_b)
{
    int bid = blockIdx.x;
    int c  = bid & (CN - 1);
    int db = (bid >> 4) & (DI / 256 - 1);
    int b  = bid >> 8;
    int d  = db * 256 + threadIdx.x;

    float s[NST];
    #pragma unroll
    for (int n = 0; n < NST; n++) s[n] = 0.f;
    for (int j = 0; j < c; j++) {
        size_t o = ((size_t)((b * CN + j) * DI) + d) * NST;
        #pragma unroll
        for (int q = 0; q < 4; q++) {
            float4 Pq = *(const float4*)&P_ws[o + q * 4];
            float4 Sq = *(const float4*)&S_ws[o + q * 4];
            s[q*4+0] = Pq.x * s[q*4+0] + Sq.x;
            s[q*4+1] = Pq.y * s[q*4+1] + Sq.y;
            s[q*4+2] = Pq.z * s[q*4+2] + Sq.z;
            s[q*4+3] = Pq.w * s[q*4+3] + Sq.w;
        }
    }

    float A[NST];
    #pragma unroll
    for (int n = 0; n < NST; n++) A[n] = -__expf(A_log[d * NST + n]);
    float Dd = Dv[d];

    const float* spb = sp + (size_t)b * LL * 160;
    size_t base = (size_t)b * LL * DI + d;
    for (int l = c * LC; l < (c + 1) * LC; l++) {
        size_t off = base + (size_t)l * DI;
        float dtv = dtr[off];
        float hsv = (float)hs_b[off];
        float dh = dtv * hsv;
        float y = 0.f;
        #pragma unroll
        for (int n = 0; n < NST; n++) {
            float a  = __expf(dtv * A[n]);
            float Bn = spb[l * 160 + RR + n];
            float Cn = spb[l * 160 + RR + NST + n];
            s[n] = a * s[n] + dh * Bn;
            y += s[n] * Cn;
        }
        float gv = (float)g_b[off];
        y_b[off] = (bf16)((y + hsv * Dd) * (gv * sigmoidf_(gv)));
    }
}

extern "C" void kernel_launch(void* const* d_in, const int* in_sizes, int n_in,
                              void* d_out, int out_size, void* d_ws, size_t ws_size,
                              hipStream_t stream)
{
    const float* x       = (const float*)d_in[0];
    const float* in_w    = (const float*)d_in[1];
    const float* in_b    = (const float*)d_in[2];
    const float* conv_w  = (const float*)d_in[3];
    const float* conv_b  = (const float*)d_in[4];
    const float* xproj_w = (const float*)d_in[5];
    const float* dt_w    = (const float*)d_in[6];
    const float* dt_b    = (const float*)d_in[7];
    const float* A_log   = (const float*)d_in[8];
    const float* Dv      = (const float*)d_in[9];
    const float* out_w   = (const float*)d_in[10];
    const float* out_b   = (const float*)d_in[11];
    float* out = (float*)d_out;

    // Overlay layout, 67.2 MB peak (same proven footprint).
    // [0,4):  x_b (D0-D1)    [0,16): spS (D3-D4) / P[0,8)+S[8,16) (D6-D7) / oS2[0,4)+oS3[4,8) (D9)
    // [16,48): in_w_b (D0-D1); then y_b [16,24) (D7-D9), hs_b [24,32) (D2-D7) -> oS0[24,28)+oS1[28,32),
    //          dt_f [32,48) (D5-D7) -> ow_b (D8-D9)
    // [48,56): h_b (D1-D2)   [56,64): g_b (D1-D7)
    // [64,~67.2): sp_f, ts_b, xw_b, dtw_b
    char* ws = (char*)d_ws;
    const size_t MB = 1u << 20;
    bf16*  x_b    = (bf16*)(ws);
    float* spS    = (float*)(ws);
    float* P_ws   = (float*)(ws);
    float* S_ws   = (float*)(ws + 8 * MB);
    fp16*  oS2    = (fp16*)(ws);
    fp16*  oS3    = (fp16*)(ws + 4 * MB);
    bf16*  in_w_b = (bf16*)(ws + 16 * MB);
    bf16*  y_b    = (bf16*)(ws + 16 * MB);
    bf16*  hs_b   = (bf16*)(ws + 24 * MB);
    fp16*  oS0    = (fp16*)(ws + 24 * MB);
    fp16*  oS1    = (fp16*)(ws + 28 * MB);
    float* dt_f   = (float*)(ws + 32 * MB);
    bf16*  ow_b   = (bf16*)(ws + 32 * MB);
    bf16*  h_b    = (bf16*)(ws + 48 * MB);
    bf16*  g_b    = (bf16*)(ws + 56 * MB);
    char* p = ws + 64 * MB;
    float* sp_f = (float*)p; p += (size_t)BLM * 160 * 4;        // 0.625 MB
    bf16*  ts_b = (bf16*)p;  p += (size_t)BLM * RR * 2;         // 0.25 MB
    bf16*  xw_b = (bf16*)p;  p += (size_t)(RR + 2 * NST) * DI * 2;  // 1.25 MB
    bf16*  dtw_b= (bf16*)p;  p += (size_t)DI * RR * 2;          // 1 MB

    // D0: fused convert x + in_w + xproj_w + dt_w to bf16
    cvt_all<<<2048, 256, 0, stream>>>(
        x, x_b, BLM * HH / 4,
        in_w, in_w_b, 2 * DI * HH / 4,
        xproj_w, xw_b, (RR + 2 * NST) * DI / 4,
        dt_w, dtw_b, DI * RR / 4);
    // D1: proj = x @ in_w^T + in_b -> h bf16, gate bf16 (BN=64: 1024 blocks, 4/CU)
    gemm_bf16<128, 64, MODE_PROJ><<<dim3((2 * DI) / 64, BLM / 128, 1), 256, 0, stream>>>(
        x_b, in_w_b, 2 * DI, HH, HH, HH, in_b, nullptr, g_b, h_b,
        nullptr, nullptr, nullptr, nullptr);
    // D2: conv + silu -> hs bf16
    conv_silu<<<(BLM * DI) / 256, 256, 0, stream>>>(h_b, conv_w, conv_b, hs_b);
    // D3: sp partials (BM=64, split-K=16, plain stores)
    gemm_bf16<64, 128, MODE_XPROJ><<<dim3(2, BLM / 64, ZXP), 256, 0, stream>>>(
        hs_b, xw_b, RR + 2 * NST, DI, DI, DI, nullptr, spS, nullptr, nullptr,
        nullptr, nullptr, nullptr, nullptr);
    // D4: reduce slices -> sp fp32 + ts bf16
    reduce_sp<<<160, 256, 0, stream>>>(spS, sp_f, ts_b);
    // D5: dt = softplus(ts @ dt_w^T + dt_b)
    gemm_bf16<64, 128, MODE_DT><<<dim3(DI / 128, BLM / 64, 1), 256, 0, stream>>>(
        ts_b, dtw_b, DI, RR, RR, RR, dt_b, dt_f, nullptr, nullptr,
        nullptr, nullptr, nullptr, nullptr);
    // D6-D7: chunked scan -> y bf16
    scan_part1<<<BB * (DI / 256) * CN, 256, 0, stream>>>(
        dt_f, sp_f, hs_b, A_log, P_ws, S_ws);
    scan_part2<<<BB * (DI / 256) * CN, 256, 0, stream>>>(
        dt_f, sp_f, hs_b, g_b, A_log, Dv, P_ws, S_ws, y_b);
    // D8: convert out_w (over dead dt region)
    cvt_f32_bf16<<<512, 256, 0, stream>>>(out_w, ow_b, HH * DI / 4);
    // D9: out partials (BN=64, split-K=4 -> 1024 blocks; fp16 per-slice stores)
    gemm_bf16<128, 64, MODE_OUT><<<dim3(HH / 64, BLM / 128, ZOUT), 256, 0, stream>>>(
        y_b, ow_b, HH, DI, DI, DI, nullptr, nullptr, nullptr, nullptr,
        oS0, oS1, oS2, oS3);
    // D10: reduce fp16 + bias -> d_out
    reduce_out<<<1024, 256, 0, stream>>>(oS0, oS1, oS2, oS3, out_b, out);
}

// Round 10
// 364.438 us; speedup vs baseline: 3.0484x; 1.0106x over previous
//
#include <hip/hip_runtime.h>
#include <hip/hip_bf16.h>

typedef __hip_bfloat16 bf16;
typedef _Float16 fp16;
typedef short bf16x8 __attribute__((ext_vector_type(8)));
typedef float f32x4 __attribute__((ext_vector_type(4)));
typedef _Float16 half8 __attribute__((ext_vector_type(8)));

#define BB 2
#define LL 512
#define HH 2048
#define DI 4096
#define NST 16
#define KK 4
#define RR 128
#define BLM (BB*LL)   // 1024 rows
#define CN 16         // scan chunks
#define LC (LL/CN)    // 32 steps per chunk
#define ZXP 16        // xproj split-K
#define ZOUT 4        // out split-K
#define CONV_N (BLM*DI)
#define CVT4_N (HH*DI/4)

enum { MODE_PROJ = 0, MODE_XPROJ = 1, MODE_DT = 2, MODE_OUT = 3 };

__device__ __forceinline__ float sigmoidf_(float x) { return 1.f / (1.f + __expf(-x)); }
__device__ __forceinline__ float softplusf_(float x) {
    return fmaxf(x, 0.f) + log1pf(__expf(-fabsf(x)));
}
__device__ __forceinline__ unsigned int bfpack(float a, float b) {
    __hip_bfloat162 h = __float22bfloat162_rn(make_float2(a, b));
    union { __hip_bfloat162 h; unsigned int u; } cv; cv.h = h;
    return cv.u;
}

typedef const __attribute__((address_space(1))) unsigned int* gas_t;
typedef __attribute__((address_space(3))) unsigned int* las_t;
__device__ __forceinline__ void gld16(const void* g, void* l) {
    __builtin_amdgcn_global_load_lds((gas_t)g, (las_t)l, 16, 0, 0);
}

__device__ __forceinline__ void cvt_seg(const float* s, bf16* d, int i) {
    float4 v = ((const float4*)s)[i];
    uint2 o; o.x = bfpack(v.x, v.y); o.y = bfpack(v.z, v.w);
    ((uint2*)d)[i] = o;
}

// fused fp32->bf16 for 4 tensors, grid-stride over concatenated float4 ranges
__global__ __launch_bounds__(256) void cvt_all(
    const float* __restrict__ s0, bf16* __restrict__ d0, int n0,
    const float* __restrict__ s1, bf16* __restrict__ d1, int n1,
    const float* __restrict__ s2, bf16* __restrict__ d2, int n2,
    const float* __restrict__ s3, bf16* __restrict__ d3, int n3)
{
    int i = blockIdx.x * 256 + threadIdx.x;
    int stride = gridDim.x * 256;
    int t1 = n0 + n1, t2 = t1 + n2, t3 = t2 + n3;
    for (; i < t3; i += stride) {
        if      (i < n0) cvt_seg(s0, d0, i);
        else if (i < t1) cvt_seg(s1, d1, i - n0);
        else if (i < t2) cvt_seg(s2, d2, i - t1);
        else             cvt_seg(s3, d3, i - t2);
    }
}

// C = A(M,K;lda)bf16 @ B(N,K;ldb)^T bf16, fp32 accum, global_load_lds staging.
// blockIdx.x = COL tile (XCD swizzle), blockIdx.y = row tile, blockIdx.z = split-K.
template<int BM, int BN, int MODE>
__global__ __launch_bounds__(256) void gemm_bf16(
    const bf16* __restrict__ A, const bf16* __restrict__ Bw,
    int N, int K, int lda, int ldb,
    const float* __restrict__ bias,
    bf16* __restrict__ outh, bf16* __restrict__ outh2,
    fp16* __restrict__ s0, fp16* __restrict__ s1,
    fp16* __restrict__ s2, fp16* __restrict__ s3)
{
    __shared__ short sA[BM * 32];
    __shared__ short sB[BN * 32];
    const int tid = threadIdx.x;
    const int col0 = blockIdx.x * BN;
    const int row0 = blockIdx.y * BM;
    const int wave = tid >> 6;
    const int lane = tid & 63;
    constexpr int NJ = (BM == 64 || BN == 64) ? 2 : 4;
    const int wr = (BM == 128) ? ((wave >> 1) * 64) : 0;
    const int wc = (BM == 64) ? (wave * 32) : ((wave & 1) * (BN / 2));
    const int lr = lane & 15;
    const int kq = (lane >> 4) << 3;

    const int kpb = K / gridDim.z;
    const int kbeg = blockIdx.z * kpb;
    const int kend = kbeg + kpb;

    const int r0 = tid >> 2;            // 0..63
    const int kc = (tid & 3) << 3;      // 0,8,16,24

    f32x4 acc[4][NJ] = {};

    for (int k0 = kbeg; k0 < kend; k0 += 32) {
        #pragma unroll
        for (int p = 0; p < BM / 64; p++) {
            int r = r0 + p * 64;
            gld16(A + (size_t)(row0 + r) * lda + k0 + kc, &sA[r * 32 + kc]);
        }
        #pragma unroll
        for (int p = 0; p < BN / 64; p++) {
            int rr = r0 + p * 64;
            int nb = col0 + rr; if (nb > N - 1) nb = N - 1;   // clamp (epilogue guards)
            gld16(Bw + (size_t)nb * ldb + k0 + kc, &sB[rr * 32 + kc]);
        }
        __syncthreads();
        bf16x8 af[4], bfr[NJ];
        #pragma unroll
        for (int i = 0; i < 4; i++)
            af[i] = *(const bf16x8*)(&sA[(wr + i * 16 + lr) * 32 + kq]);
        #pragma unroll
        for (int j = 0; j < NJ; j++)
            bfr[j] = *(const bf16x8*)(&sB[(wc + j * 16 + lr) * 32 + kq]);
        #pragma unroll
        for (int i = 0; i < 4; i++)
            #pragma unroll
            for (int j = 0; j < NJ; j++)
                acc[i][j] = __builtin_amdgcn_mfma_f32_16x16x32_bf16(af[i], bfr[j], acc[i][j], 0, 0, 0);
        __syncthreads();
    }

    fp16* oslice = s0;
    if (MODE == MODE_OUT) {
        int z = blockIdx.z;
        oslice = (z == 0) ? s0 : (z == 1) ? s1 : (z == 2) ? s2 : s3;
    }
    const int drow = (lane >> 4) << 2;
    const int dcol = lane & 15;
    #pragma unroll
    for (int i = 0; i < 4; i++) {
        #pragma unroll
        for (int j = 0; j < NJ; j++) {
            int n = col0 + wc + j * 16 + dcol;
            if (n >= N) continue;
            float bv = bias ? bias[n] : 0.f;
            #pragma unroll
            for (int r = 0; r < 4; r++) {
                int m = row0 + wr + i * 16 + drow + r;
                float v = acc[i][j][r];
                if (MODE == MODE_PROJ) {
                    v += bv;
                    if (n < DI) outh2[(size_t)m * DI + n] = (bf16)v;         // h bf16
                    else        outh[(size_t)m * DI + (n - DI)] = (bf16)v;   // gate bf16
                } else if (MODE == MODE_XPROJ) {
                    s0[(size_t)blockIdx.z * (BLM * 160) + (size_t)m * 160 + n] = (fp16)v;
                } else if (MODE == MODE_DT) {
                    s0[(size_t)m * DI + n] = (fp16)softplusf_(v + bv);       // dt fp16
                } else { // MODE_OUT: fp16 per-slice partial
                    oslice[(size_t)m * HH + n] = (fp16)v;
                }
            }
        }
    }
}

// fused: depthwise causal conv K=4 + silu (bf16 h -> bf16 hs)  AND  out_w fp32->bf16
__global__ __launch_bounds__(256) void conv_cvtow(
    const bf16* __restrict__ h, const float* __restrict__ conv_w,
    const float* __restrict__ conv_b, bf16* __restrict__ hs_b,
    const float* __restrict__ ow, bf16* __restrict__ ow_b)
{
    int i = blockIdx.x * 256 + threadIdx.x;
    int stride = gridDim.x * 256;
    for (; i < CONV_N + CVT4_N; i += stride) {
        if (i < CONV_N) {
            int idx = i;
            int d = idx & (DI - 1);
            int l = (idx >> 12) & (LL - 1);
            float acc = conv_b[d];
            #pragma unroll
            for (int k = 0; k < KK; k++) {
                int ls = l - (KK - 1) + k;
                if (ls >= 0) acc += (float)h[(size_t)idx + (size_t)(ls - l) * DI] * conv_w[d * KK + k];
            }
            float s = acc * sigmoidf_(acc);
            hs_b[idx] = (bf16)s;
        } else {
            cvt_seg(ow, ow_b, i - CONV_N);
        }
    }
}

// sum 16 fp16 xproj slices -> sp fp32; cols<128 also -> ts bf16 (8 cols/thread)
__global__ __launch_bounds__(256) void reduce_sp(
    const fp16* __restrict__ spS, float* __restrict__ sp_f, bf16* __restrict__ ts_b)
{
    int i = blockIdx.x * 256 + threadIdx.x;     // 20480 groups of 8
    int row = i / 20, c8 = (i % 20) * 8;
    float r[8] = {};
    #pragma unroll
    for (int z = 0; z < ZXP; z++) {
        half8 v = *(const half8*)&spS[(size_t)z * (BLM * 160) + (size_t)row * 160 + c8];
        #pragma unroll
        for (int e = 0; e < 8; e++) r[e] += (float)v[e];
    }
    *(float4*)&sp_f[(size_t)row * 160 + c8]     = make_float4(r[0], r[1], r[2], r[3]);
    *(float4*)&sp_f[(size_t)row * 160 + c8 + 4] = make_float4(r[4], r[5], r[6], r[7]);
    if (c8 < RR) {
        uint4 o = make_uint4(bfpack(r[0], r[1]), bfpack(r[2], r[3]),
                             bfpack(r[4], r[5]), bfpack(r[6], r[7]));
        *(uint4*)&ts_b[(size_t)row * RR + c8] = o;
    }
}

// sum 4 fp16 out slices + bias -> d_out fp32 (8 elems/thread)
__global__ __launch_bounds__(256) void reduce_out(
    const fp16* __restrict__ s0, const fp16* __restrict__ s1,
    const fp16* __restrict__ s2, const fp16* __restrict__ s3,
    const float* __restrict__ bias, float* __restrict__ out)
{
    int i = blockIdx.x * 256 + threadIdx.x;     // 262144 groups of 8
    int c8 = (i & 255) << 3;
    half8 a = ((const half8*)s0)[i];
    half8 b = ((const half8*)s1)[i];
    half8 c = ((const half8*)s2)[i];
    half8 d = ((const half8*)s3)[i];
    float r[8];
    #pragma unroll
    for (int e = 0; e < 8; e++)
        r[e] = (float)a[e] + (float)b[e] + (float)c[e] + (float)d[e] + bias[c8 + e];
    ((float4*)out)[2 * i]     = make_float4(r[0], r[1], r[2], r[3]);
    ((float4*)out)[2 * i + 1] = make_float4(r[4], r[5], r[6], r[7]);
}

// Chunked scan pass 1: per (b,d,chunk) thread; dt fp16; P/S plane-major [(b,c,n)][d].
__global__ __launch_bounds__(256) void scan_part1(
    const fp16* __restrict__ dtr, const float* __restrict__ sp,
    const bf16* __restrict__ hs_b, const float* __restrict__ A_log,
    float* __restrict__ P_ws, float* __restrict__ S_ws)
{
    int bid = blockIdx.x;
    int c  = bid & (CN - 1);
    int db = (bid >> 4) & (DI / 256 - 1);
    int b  = bid >> 8;
    int d  = db * 256 + threadIdx.x;

    float A[NST], P[NST], S[NST];
    #pragma unroll
    for (int n = 0; n < NST; n++) {
        A[n] = -__expf(A_log[d * NST + n]);
        P[n] = 1.f; S[n] = 0.f;
    }
    const float* spb = sp + (size_t)b * LL * 160;
    size_t base = (size_t)b * LL * DI + d;
    for (int l = c * LC; l < (c + 1) * LC; l++) {
        size_t off = base + (size_t)l * DI;
        float dtv = (float)dtr[off];
        float hsv = (float)hs_b[off];
        float dh = dtv * hsv;
        #pragma unroll
        for (int n = 0; n < NST; n++) {
            float a  = __expf(dtv * A[n]);
            float Bn = spb[l * 160 + RR + n];
            S[n] = a * S[n] + dh * Bn;
            P[n] *= a;
        }
    }
    size_t ob = (size_t)(b * CN + c) * NST * DI + d;
    #pragma unroll
    for (int n = 0; n < NST; n++) {
        P_ws[ob + (size_t)n * DI] = P[n];
        S_ws[ob + (size_t)n * DI] = S[n];
    }
}

// Pass 2: rebuild chunk-initial state (coalesced plane-major P/S), local scan, emit y bf16.
__global__ __launch_bounds__(256) void scan_part2(
    const fp16* __restrict__ dtr, const float* __restrict__ sp,
    const bf16* __restrict__ hs_b, const bf16* __restrict__ g_b,
    const float* __restrict__ A_log, const float* __restrict__ Dv,
    const float* __restrict__ P_ws, const float* __restrict__ S_ws,
    bf16* __restrict__ y_b)
{
    int bid = blockIdx.x;
    int c  = bid & (CN - 1);
    int db = (bid >> 4) & (DI / 256 - 1);
    int b  = bid >> 8;
    int d  = db * 256 + threadIdx.x;

    float s[NST];
    #pragma unroll
    for (int n = 0; n < NST; n++) s[n] = 0.f;
    for (int j = 0; j < c; j++) {
        size_t ojb = (size_t)(b * CN + j) * NST * DI + d;
        #pragma unroll
        for (int n = 0; n < NST; n++)
            s[n] = P_ws[ojb + (size_t)n * DI] * s[n] + S_ws[ojb + (size_t)n * DI];
    }

    float A[NST];
    #pragma unroll
    for (int n = 0; n < NST; n++) A[n] = -__expf(A_log[d * NST + n]);
    float Dd = Dv[d];

    const float* spb = sp + (size_t)b * LL * 160;
    size_t base = (size_t)b * LL * DI + d;
    for (int l = c * LC; l < (c + 1) * LC; l++) {
        size_t off = base + (size_t)l * DI;
        float dtv = (float)dtr[off];
        float hsv = (float)hs_b[off];
        float dh = dtv * hsv;
        float y = 0.f;
        #pragma unroll
        for (int n = 0; n < NST; n++) {
            float a  = __expf(dtv * A[n]);
            float Bn = spb[l * 160 + RR + n];
            float Cn = spb[l * 160 + RR + NST + n];
            s[n] = a * s[n] + dh * Bn;
            y += s[n] * Cn;
        }
        float gv = (float)g_b[off];
        y_b[off] = (bf16)((y + hsv * Dd) * (gv * sigmoidf_(gv)));
    }
}

extern "C" void kernel_launch(void* const* d_in, const int* in_sizes, int n_in,
                              void* d_out, int out_size, void* d_ws, size_t ws_size,
                              hipStream_t stream)
{
    const float* x       = (const float*)d_in[0];
    const float* in_w    = (const float*)d_in[1];
    const float* in_b    = (const float*)d_in[2];
    const float* conv_w  = (const float*)d_in[3];
    const float* conv_b  = (const float*)d_in[4];
    const float* xproj_w = (const float*)d_in[5];
    const float* dt_w    = (const float*)d_in[6];
    const float* dt_b    = (const float*)d_in[7];
    const float* A_log   = (const float*)d_in[8];
    const float* Dv      = (const float*)d_in[9];
    const float* out_w   = (const float*)d_in[10];
    const float* out_b   = (const float*)d_in[11];
    float* out = (float*)d_out;

    // Overlay layout, 67.2 MB peak.
    // [0,8):   h_b (D1-D2) -> spS fp16 5.25 (D3-D4) -> P (D6-D7) -> oS0[0,4)+oS1[4,8) (D8-D9)
    // [8,16):  x_b [8,12) (D0-D1) -> S (D6-D7) -> oS2[8,12)+oS3[12,16) (D8-D9)
    // [16,32): in_w_b part (D0-D1) -> ow_b bf16 (D2-D8)
    // [32,40): in_w_b part -> y_b (D7-D8)
    // [40,48): in_w_b part -> dt_h fp16 (D5-D7)
    // [48,56): hs_b (D2-D7)
    // [56,64): g_b (D1-D7)
    // [64,67.2): sp_f, ts_b, xw_b, dtw_b
    char* ws = (char*)d_ws;
    const size_t MB = 1u << 20;
    bf16*  h_b    = (bf16*)(ws);
    fp16*  spS    = (fp16*)(ws);
    float* P_ws   = (float*)(ws);
    fp16*  oS0    = (fp16*)(ws);
    fp16*  oS1    = (fp16*)(ws + 4 * MB);
    bf16*  x_b    = (bf16*)(ws + 8 * MB);
    float* S_ws   = (float*)(ws + 8 * MB);
    fp16*  oS2    = (fp16*)(ws + 8 * MB);
    fp16*  oS3    = (fp16*)(ws + 12 * MB);
    bf16*  in_w_b = (bf16*)(ws + 16 * MB);
    bf16*  ow_b   = (bf16*)(ws + 16 * MB);
    bf16*  y_b    = (bf16*)(ws + 32 * MB);
    fp16*  dt_h   = (fp16*)(ws + 40 * MB);
    bf16*  hs_b   = (bf16*)(ws + 48 * MB);
    bf16*  g_b    = (bf16*)(ws + 56 * MB);
    char* p = ws + 64 * MB;
    float* sp_f = (float*)p; p += (size_t)BLM * 160 * 4;        // 0.625 MB
    bf16*  ts_b = (bf16*)p;  p += (size_t)BLM * RR * 2;         // 0.25 MB
    bf16*  xw_b = (bf16*)p;  p += (size_t)(RR + 2 * NST) * DI * 2;  // 1.25 MB
    bf16*  dtw_b= (bf16*)p;  p += (size_t)DI * RR * 2;          // 1 MB

    // D0: fused convert x + in_w + xproj_w + dt_w to bf16
    cvt_all<<<2048, 256, 0, stream>>>(
        x, x_b, BLM * HH / 4,
        in_w, in_w_b, 2 * DI * HH / 4,
        xproj_w, xw_b, (RR + 2 * NST) * DI / 4,
        dt_w, dtw_b, DI * RR / 4);
    // D1: proj = x @ in_w^T + in_b -> h bf16, gate bf16
    gemm_bf16<128, 64, MODE_PROJ><<<dim3((2 * DI) / 64, BLM / 128, 1), 256, 0, stream>>>(
        x_b, in_w_b, 2 * DI, HH, HH, HH, in_b, g_b, h_b,
        nullptr, nullptr, nullptr, nullptr);
    // D2: conv+silu -> hs bf16; fused out_w fp32->bf16
    conv_cvtow<<<2048, 256, 0, stream>>>(h_b, conv_w, conv_b, hs_b, out_w, ow_b);
    // D3: sp partials fp16 (BM=64, split-K=16)
    gemm_bf16<64, 128, MODE_XPROJ><<<dim3(2, BLM / 64, ZXP), 256, 0, stream>>>(
        hs_b, xw_b, RR + 2 * NST, DI, DI, DI, nullptr, nullptr, nullptr,
        spS, nullptr, nullptr, nullptr);
    // D4: reduce fp16 slices -> sp fp32 + ts bf16
    reduce_sp<<<80, 256, 0, stream>>>(spS, sp_f, ts_b);
    // D5: dt = softplus(ts @ dt_w^T + dt_b) -> fp16
    gemm_bf16<64, 128, MODE_DT><<<dim3(DI / 128, BLM / 64, 1), 256, 0, stream>>>(
        ts_b, dtw_b, DI, RR, RR, RR, dt_b, nullptr, nullptr,
        dt_h, nullptr, nullptr, nullptr);
    // D6-D7: chunked scan -> y bf16
    scan_part1<<<BB * (DI / 256) * CN, 256, 0, stream>>>(
        dt_h, sp_f, hs_b, A_log, P_ws, S_ws);
    scan_part2<<<BB * (DI / 256) * CN, 256, 0, stream>>>(
        dt_h, sp_f, hs_b, g_b, A_log, Dv, P_ws, S_ws, y_b);
    // D8: out partials (BN=64, split-K=4; fp16 per-slice stores)
    gemm_bf16<128, 64, MODE_OUT><<<dim3(HH / 64, BLM / 128, ZOUT), 256, 0, stream>>>(
        y_b, ow_b, HH, DI, DI, DI, nullptr, nullptr, nullptr,
        oS0, oS1, oS2, oS3);
    // D9: reduce fp16 + bias -> d_out
    reduce_out<<<1024, 256, 0, stream>>>(oS0, oS1, oS2, oS3, out_b, out);
}